// Round 1
// baseline (7736.484 us; speedup 1.0000x reference)
//
#include <hip/hip_runtime.h>
#include <stdint.h>

// Problem constants (match reference)
#define B_ROWS 16384
#define V_DIM  1024
#define H_DIM  1024
#define C_DIM  64
#define P_COLS 4096   // 2*(V+H)
#define K_STEPS 25

typedef __bf16 bf16_t;
typedef bf16_t bf16x8 __attribute__((ext_vector_type(8)));
typedef float  f32x4  __attribute__((ext_vector_type(4)));

// ---------------------------------------------------------------------------
// Counter-based RNG: lowbias32-style hash. Unbiased uniform in [0,1).
// Chains are independent per element; distribution matches jax.random in law,
// which is all the mean-over-16384-chains loss needs (SE ~0.5 << tol 15.28).
// ---------------------------------------------------------------------------
__device__ __forceinline__ float rng_u01(uint32_t idx, uint32_t tag) {
    uint32_t x = idx * 0x9E3779B9u ^ (tag * 0x85EBCA6Bu + 0xC2B2AE35u);
    x ^= x >> 16; x *= 0x7FEB352Du;
    x ^= x >> 15; x *= 0x846CA68Bu;
    x ^= x >> 16;
    return (float)(x >> 8) * 5.9604644775390625e-8f; // /2^24
}

// async global->LDS, 16B per lane. LDS dst = wave-uniform base + lane*16.
__device__ __forceinline__ void load_lds16(const void* g, void* l) {
    __builtin_amdgcn_global_load_lds(
        (__attribute__((address_space(1))) void*)(uintptr_t)(g),
        (__attribute__((address_space(3))) void*)(l),
        16, 0, 0);
}

__device__ __forceinline__ float softplus_f(float x) {
    return fmaxf(x, 0.0f) + log1pf(__expf(-fabsf(x)));
}

// ---------------------------------------------------------------------------
// GEMM C = A (MxK) * Bt^T (Bt is NxK row-major), fused epilogue.
// MODE 0: out = bernoulli(sigmoid(C + mod)) as bf16   (Gibbs sampling step)
// MODE 1: atomicAdd(out_scalar, scale * sum(softplus(C + mod)))  (free energy)
// 128x128 tile, BK=32, 4 waves, each wave 64x64 via 4x4 mfma_f32_16x16x32_bf16
// ---------------------------------------------------------------------------
template <int MODE>
__global__ __launch_bounds__(256, 2) void gemm_ep(
    const bf16_t* __restrict__ A, const bf16_t* __restrict__ Bt,
    const float* __restrict__ mod, bf16_t* __restrict__ out_s,
    float* __restrict__ out_scalar, int M, int N, int K,
    uint32_t tag, float scale)
{
    constexpr int BM = 128, BN = 128, BK = 32;
    __shared__ __align__(16) bf16_t sA[BM * BK];
    __shared__ __align__(16) bf16_t sB[BN * BK];

    const int tid  = threadIdx.x;
    const int wave = tid >> 6;
    const int lane = tid & 63;
    const int m0 = blockIdx.y * BM;
    const int n0 = blockIdx.x * BN;
    const int wr = (wave >> 1) * 64;   // wave's row offset in tile
    const int wc = (wave & 1) * 64;    // wave's col offset in tile
    const int cl   = lane & 15;
    const int quad = lane >> 4;

    // staging: each wave loads 32 rows of A-tile and 32 rows of Bt-tile.
    // one 16B/lane wave-load covers 16 rows (row = 32 elems = 4 lanes).
    const int srow = wave * 32 + (lane >> 2);
    const int skc  = (lane & 3) * 8;
    const bf16_t* gA0 = A  + (size_t)(m0 + srow) * K + skc;
    const bf16_t* gA1 = gA0 + (size_t)16 * K;
    const bf16_t* gB0 = Bt + (size_t)(n0 + srow) * K + skc;
    const bf16_t* gB1 = gB0 + (size_t)16 * K;
    bf16_t* lA0 = sA + (wave * 32) * BK;
    bf16_t* lA1 = sA + (wave * 32 + 16) * BK;
    bf16_t* lB0 = sB + (wave * 32) * BK;
    bf16_t* lB1 = sB + (wave * 32 + 16) * BK;

    f32x4 acc[4][4] = {};

    for (int kt = 0; kt < K; kt += BK) {
        load_lds16(gA0 + kt, lA0);
        load_lds16(gA1 + kt, lA1);
        load_lds16(gB0 + kt, lB0);
        load_lds16(gB1 + kt, lB1);
        __syncthreads();   // drains vmcnt before barrier (compiler-inserted)

        bf16x8 af[4], bfr[4];
#pragma unroll
        for (int mi = 0; mi < 4; ++mi)
            af[mi] = *(const bf16x8*)(sA + (wr + mi * 16 + cl) * BK + quad * 8);
#pragma unroll
        for (int ni = 0; ni < 4; ++ni)
            bfr[ni] = *(const bf16x8*)(sB + (wc + ni * 16 + cl) * BK + quad * 8);
#pragma unroll
        for (int mi = 0; mi < 4; ++mi)
#pragma unroll
            for (int ni = 0; ni < 4; ++ni)
                acc[mi][ni] = __builtin_amdgcn_mfma_f32_16x16x32_bf16(
                    af[mi], bfr[ni], acc[mi][ni], 0, 0, 0);
        __syncthreads();
    }

    // Epilogue. C/D layout: col = lane&15, row = quad*4 + reg  [m89/m91]
    const int row_base = m0 + wr + quad * 4;
    const int col_base = n0 + wc + cl;

    if (MODE == 0) {
#pragma unroll
        for (int mi = 0; mi < 4; ++mi) {
#pragma unroll
            for (int ni = 0; ni < 4; ++ni) {
#pragma unroll
                for (int r = 0; r < 4; ++r) {
                    int row = row_base + mi * 16 + r;
                    int col = col_base + ni * 16;
                    size_t o = (size_t)row * N + col;
                    float x = acc[mi][ni][r] + mod[o];
                    float p = 1.0f / (1.0f + __expf(-x));
                    float u = rng_u01((uint32_t)o, tag);
                    out_s[o] = (u < p) ? (bf16_t)1.0f : (bf16_t)0.0f;
                }
            }
        }
    } else {
        float local = 0.0f;
#pragma unroll
        for (int mi = 0; mi < 4; ++mi) {
#pragma unroll
            for (int ni = 0; ni < 4; ++ni) {
#pragma unroll
                for (int r = 0; r < 4; ++r) {
                    int row = row_base + mi * 16 + r;
                    int col = col_base + ni * 16;
                    size_t o = (size_t)row * N + col;
                    local += softplus_f(acc[mi][ni][r] + mod[o]);
                }
            }
        }
        local *= scale;
        for (int off = 32; off > 0; off >>= 1)
            local += __shfl_down(local, off, 64);
        if (lane == 0) atomicAdd(out_scalar, local);
    }
}

// ---------------------------------------------------------------------------
// W (VxH fp32) -> Wb = bf16(W) (VxH) and Wtb = bf16(W^T) (HxV), LDS transpose
// ---------------------------------------------------------------------------
__global__ void wconv_kernel(const float* __restrict__ W,
                             bf16_t* __restrict__ Wb, bf16_t* __restrict__ Wtb) {
    __shared__ float tile[32][33];
    int bx = blockIdx.x * 32, by = blockIdx.y * 32;
    int tx = threadIdx.x & 31, ty = threadIdx.x >> 5;
#pragma unroll
    for (int r = ty; r < 32; r += 8) {
        float v = W[(size_t)(by + r) * H_DIM + bx + tx];
        Wb[(size_t)(by + r) * H_DIM + bx + tx] = (bf16_t)v;
        tile[r][tx] = v;
    }
    __syncthreads();
#pragma unroll
    for (int r = ty; r < 32; r += 8)
        Wtb[(size_t)(bx + r) * V_DIM + by + tx] = (bf16_t)tile[tx][r];
}

// h1 = tanh(cond @ W1 + b1), one lane per (row, j)
__global__ void h1_kernel(const float* __restrict__ cond, const float* __restrict__ W1,
                          const float* __restrict__ b1, float* __restrict__ h1) {
    int row = blockIdx.x * 4 + (threadIdx.x >> 6);
    int j   = threadIdx.x & 63;
    const float* cr = cond + (size_t)row * C_DIM;
    float s = b1[j];
#pragma unroll 8
    for (int k = 0; k < C_DIM; ++k) s = fmaf(cr[k], W1[k * 64 + j], s);
    h1[(size_t)row * 64 + j] = tanhf(s);
}

// b_mod[i,v] = (1+gamma_b)*b[v] + beta_b ; c_mod[i,h] = (1+gamma_c)*c[h] + beta_c
// gamma/beta come from h1[i] . W2[:, col] + b2[col]; cols per reference slicing.
__global__ void mods_kernel(const float* __restrict__ h1, const float* __restrict__ W2,
                            const float* __restrict__ b2, const float* __restrict__ b,
                            const float* __restrict__ c, float* __restrict__ b_mod,
                            float* __restrict__ c_mod) {
    size_t gid = (size_t)blockIdx.x * 256 + threadIdx.x;   // B * 2048
    int row = (int)(gid >> 11);
    int j   = (int)(gid & 2047);
    const float* h = h1 + (size_t)row * 64;
    int gcol, bcol, dj; const float* baseptr; float* dst;
    if (j < V_DIM) { dj = j;         gcol = dj;                     bcol = V_DIM + dj;             dst = b_mod; baseptr = b; }
    else           { dj = j - V_DIM; gcol = 2 * V_DIM + dj;         bcol = 2 * V_DIM + H_DIM + dj; dst = c_mod; baseptr = c; }
    float g = b2[gcol], be = b2[bcol];
#pragma unroll 8
    for (int k = 0; k < 64; ++k) {
        float hv = h[k];
        g  = fmaf(hv, W2[k * P_COLS + gcol], g);
        be = fmaf(hv, W2[k * P_COLS + bcol], be);
    }
    dst[(size_t)row * 1024 + dj] = (1.0f + g) * baseptr[dj] + be;
}

__global__ void initv_kernel(bf16_t* __restrict__ v, uint32_t tag) {
    uint32_t i = blockIdx.x * 256 + threadIdx.x;
    v[i] = (rng_u01(i, tag) < 0.5f) ? (bf16_t)1.0f : (bf16_t)0.0f;
}

__global__ void cast_kernel(const float* __restrict__ src, bf16_t* __restrict__ dst) {
    size_t i = (size_t)blockIdx.x * 256 + threadIdx.x;
    dst[i] = (bf16_t)src[i];  // 0/1 exact
}

// out += scale * sum((v_model - v_data) * b_mod)
__global__ void bdot_kernel(const bf16_t* __restrict__ vm, const float* __restrict__ vd,
                            const float* __restrict__ bm, float* __restrict__ out,
                            float scale) {
    size_t i = (size_t)blockIdx.x * 256 + threadIdx.x;
    float local = ((float)vm[i] - vd[i]) * bm[i] * scale;
    for (int off = 32; off > 0; off >>= 1)
        local += __shfl_down(local, off, 64);
    if ((threadIdx.x & 63) == 0) atomicAdd(out, local);
}

// ---------------------------------------------------------------------------
extern "C" void kernel_launch(void* const* d_in, const int* in_sizes, int n_in,
                              void* d_out, int out_size, void* d_ws, size_t ws_size,
                              hipStream_t stream) {
    (void)in_sizes; (void)n_in; (void)out_size; (void)ws_size;
    const float* v_data = (const float*)d_in[0];
    const float* cond   = (const float*)d_in[1];
    const float* W      = (const float*)d_in[2];
    const float* b      = (const float*)d_in[3];
    const float* c      = (const float*)d_in[4];
    const float* W1     = (const float*)d_in[5];
    const float* b1     = (const float*)d_in[6];
    const float* W2     = (const float*)d_in[7];
    const float* b2     = (const float*)d_in[8];
    float* out = (float*)d_out;
    char*  ws  = (char*)d_ws;

    const size_t MB = 1024 * 1024;
    bf16_t* Wb    = (bf16_t*)(ws + 0 * MB);    //  2 MB  bf16 W   (VxH)
    bf16_t* Wtb   = (bf16_t*)(ws + 2 * MB);    //  2 MB  bf16 W^T (HxV)
    float*  h1    = (float*) (ws + 4 * MB);    //  4 MB  tanh(cond@W1+b1)
    float*  b_mod = (float*) (ws + 8 * MB);    // 64 MB  (B x V) fp32
    float*  c_mod = (float*) (ws + 72 * MB);   // 64 MB  (B x H) fp32
    bf16_t* vbuf  = (bf16_t*)(ws + 136 * MB);  // 32 MB  (B x V) bf16
    bf16_t* hbuf  = (bf16_t*)(ws + 168 * MB);  // 32 MB  (B x H) bf16 (+v_data cast)
    // total 200 MB

    hipMemsetAsync(d_out, 0, sizeof(float), stream);

    wconv_kernel<<<dim3(32, 32), 256, 0, stream>>>(W, Wb, Wtb);
    h1_kernel<<<B_ROWS / 4, 256, 0, stream>>>(cond, W1, b1, h1);
    mods_kernel<<<(B_ROWS * 2048) / 256, 256, 0, stream>>>(h1, W2, b2, b, c, b_mod, c_mod);
    initv_kernel<<<(B_ROWS * V_DIM) / 256, 256, 0, stream>>>(vbuf, 7u);

    dim3 ggrid(H_DIM / 128, B_ROWS / 128);  // 8 x 128 = 1024 blocks
    const float invB = 1.0f / (float)B_ROWS;

    for (int k = 0; k < K_STEPS; ++k) {
        // h ~ Bern(sigmoid(v @ W + c_mod)) : A=v, Bt=W^T(bf16, HxV)
        gemm_ep<0><<<ggrid, 256, 0, stream>>>(vbuf, Wtb, c_mod, hbuf, nullptr,
                                              B_ROWS, H_DIM, V_DIM,
                                              100u + 2u * (uint32_t)k, 0.0f);
        // v ~ Bern(sigmoid(h @ W^T + b_mod)) : A=h, Bt=W(bf16, VxH)
        gemm_ep<0><<<ggrid, 256, 0, stream>>>(hbuf, Wb, b_mod, vbuf, nullptr,
                                              B_ROWS, V_DIM, H_DIM,
                                              101u + 2u * (uint32_t)k, 0.0f);
    }

    // loss*B = sum softplus(v_model@W + c_mod) - sum softplus(v_data@W + c_mod)
    //          + sum (v_model - v_data)*b_mod
    gemm_ep<1><<<ggrid, 256, 0, stream>>>(vbuf, Wtb, c_mod, nullptr, out,
                                          B_ROWS, H_DIM, V_DIM, 0u, invB);
    cast_kernel<<<(B_ROWS * V_DIM) / 256, 256, 0, stream>>>(v_data, hbuf);
    gemm_ep<1><<<ggrid, 256, 0, stream>>>(hbuf, Wtb, c_mod, nullptr, out,
                                          B_ROWS, H_DIM, V_DIM, 1u, -invB);
    bdot_kernel<<<(B_ROWS * V_DIM) / 256, 256, 0, stream>>>(vbuf, v_data, b_mod, out, invB);
}

// Round 2
// 4147.217 us; speedup vs baseline: 1.8655x; 1.8655x over previous
//
#include <hip/hip_runtime.h>
#include <stdint.h>

// Problem constants (match reference)
#define B_ROWS 16384
#define V_DIM  1024
#define H_DIM  1024
#define C_DIM  64
#define P_COLS 4096   // 2*(V+H)
#define K_STEPS 25

typedef __bf16 bf16_t;
typedef bf16_t bf16x8 __attribute__((ext_vector_type(8)));
typedef bf16_t bf16x4 __attribute__((ext_vector_type(4)));
typedef float  f32x4  __attribute__((ext_vector_type(4)));

// ---------------------------------------------------------------------------
// Counter-based RNG: lowbias32-style hash. Unbiased uniform in [0,1).
// Chains are independent per element; distribution matches jax.random in law,
// which is all the mean-over-16384-chains loss needs (R1: absmax 0.0 vs tol 15.28).
// ---------------------------------------------------------------------------
__device__ __forceinline__ float rng_u01(uint32_t idx, uint32_t tag) {
    uint32_t x = idx * 0x9E3779B9u ^ (tag * 0x85EBCA6Bu + 0xC2B2AE35u);
    x ^= x >> 16; x *= 0x7FEB352Du;
    x ^= x >> 15; x *= 0x846CA68Bu;
    x ^= x >> 16;
    return (float)(x >> 8) * 5.9604644775390625e-8f; // /2^24
}

// async global->LDS, 16B per lane. LDS dst = wave-uniform base + lane*16.
__device__ __forceinline__ void load_lds16(const void* g, void* l) {
    __builtin_amdgcn_global_load_lds(
        (__attribute__((address_space(1))) void*)(uintptr_t)(g),
        (__attribute__((address_space(3))) void*)(l),
        16, 0, 0);
}

__device__ __forceinline__ float softplus_f(float x) {
    return fmaxf(x, 0.0f) + log1pf(__expf(-fabsf(x)));
}

// ---------------------------------------------------------------------------
// GEMM C = A (MxK) * Bt^T (Bt is NxK row-major), fused epilogue.
// MODE 0: out = bernoulli(sigmoid(C + mod)) as bf16   (Gibbs sampling step)
// MODE 1: atomicAdd(out_scalar, scale * sum(softplus(C + mod)))  (free energy)
// 128x128 tile, BK=32, 4 waves, each wave 64x64 via 4x4 mfma_f32_16x16x32_bf16
// ---------------------------------------------------------------------------
template <int MODE>
__global__ __launch_bounds__(256, 2) void gemm_ep(
    const bf16_t* __restrict__ A, const bf16_t* __restrict__ Bt,
    const float* __restrict__ mod, bf16_t* __restrict__ out_s,
    float* __restrict__ out_scalar, int M, int N, int K,
    uint32_t tag, float scale)
{
    constexpr int BM = 128, BN = 128, BK = 32;
    __shared__ __align__(16) bf16_t sA[BM * BK];
    __shared__ __align__(16) bf16_t sB[BN * BK];

    const int tid  = threadIdx.x;
    const int wave = tid >> 6;
    const int lane = tid & 63;
    const int m0 = blockIdx.y * BM;
    const int n0 = blockIdx.x * BN;
    const int wr = (wave >> 1) * 64;   // wave's row offset in tile
    const int wc = (wave & 1) * 64;    // wave's col offset in tile
    const int cl   = lane & 15;
    const int quad = lane >> 4;

    // staging: each wave loads 32 rows of A-tile and 32 rows of Bt-tile.
    // one 16B/lane wave-load covers 16 rows (row = 32 elems = 4 lanes).
    const int srow = wave * 32 + (lane >> 2);
    const int skc  = (lane & 3) * 8;
    const bf16_t* gA0 = A  + (size_t)(m0 + srow) * K + skc;
    const bf16_t* gA1 = gA0 + (size_t)16 * K;
    const bf16_t* gB0 = Bt + (size_t)(n0 + srow) * K + skc;
    const bf16_t* gB1 = gB0 + (size_t)16 * K;
    bf16_t* lA0 = sA + (wave * 32) * BK;
    bf16_t* lA1 = sA + (wave * 32 + 16) * BK;
    bf16_t* lB0 = sB + (wave * 32) * BK;
    bf16_t* lB1 = sB + (wave * 32 + 16) * BK;

    f32x4 acc[4][4] = {};

    for (int kt = 0; kt < K; kt += BK) {
        load_lds16(gA0 + kt, lA0);
        load_lds16(gA1 + kt, lA1);
        load_lds16(gB0 + kt, lB0);
        load_lds16(gB1 + kt, lB1);
        __syncthreads();   // drains vmcnt before barrier (compiler-inserted)

        bf16x8 af[4], bfr[4];
#pragma unroll
        for (int mi = 0; mi < 4; ++mi)
            af[mi] = *(const bf16x8*)(sA + (wr + mi * 16 + cl) * BK + quad * 8);
#pragma unroll
        for (int ni = 0; ni < 4; ++ni)
            bfr[ni] = *(const bf16x8*)(sB + (wc + ni * 16 + cl) * BK + quad * 8);
#pragma unroll
        for (int mi = 0; mi < 4; ++mi)
#pragma unroll
            for (int ni = 0; ni < 4; ++ni)
                acc[mi][ni] = __builtin_amdgcn_mfma_f32_16x16x32_bf16(
                    af[mi], bfr[ni], acc[mi][ni], 0, 0, 0);
        __syncthreads();
    }

    // Epilogue. C/D layout: col = lane&15, row = quad*4 + reg  [m89/m91]
    const int row_base = m0 + wr + quad * 4;
    const int col_base = n0 + wc + cl;

    if (MODE == 0) {
#pragma unroll
        for (int mi = 0; mi < 4; ++mi) {
#pragma unroll
            for (int ni = 0; ni < 4; ++ni) {
#pragma unroll
                for (int r = 0; r < 4; ++r) {
                    int row = row_base + mi * 16 + r;
                    int col = col_base + ni * 16;
                    size_t o = (size_t)row * N + col;
                    float x = acc[mi][ni][r] + mod[o];
                    float p = 1.0f / (1.0f + __expf(-x));
                    float u = rng_u01((uint32_t)o, tag);
                    out_s[o] = (u < p) ? (bf16_t)1.0f : (bf16_t)0.0f;
                }
            }
        }
    } else {
        float local = 0.0f;
#pragma unroll
        for (int mi = 0; mi < 4; ++mi) {
#pragma unroll
            for (int ni = 0; ni < 4; ++ni) {
#pragma unroll
                for (int r = 0; r < 4; ++r) {
                    int row = row_base + mi * 16 + r;
                    int col = col_base + ni * 16;
                    size_t o = (size_t)row * N + col;
                    local += softplus_f(acc[mi][ni][r] + mod[o]);
                }
            }
        }
        local *= scale;
        for (int off = 32; off > 0; off >>= 1)
            local += __shfl_down(local, off, 64);
        __shared__ float wsum[4];
        if (lane == 0) wsum[wave] = local;
        __syncthreads();
        if (tid == 0)
            atomicAdd(out_scalar, wsum[0] + wsum[1] + wsum[2] + wsum[3]);
    }
}

// ---------------------------------------------------------------------------
// W (VxH fp32) -> Wb = bf16(W) (VxH) and Wtb = bf16(W^T) (HxV), LDS transpose
// ---------------------------------------------------------------------------
__global__ void wconv_kernel(const float* __restrict__ W,
                             bf16_t* __restrict__ Wb, bf16_t* __restrict__ Wtb) {
    __shared__ float tile[32][33];
    int bx = blockIdx.x * 32, by = blockIdx.y * 32;
    int tx = threadIdx.x & 31, ty = threadIdx.x >> 5;
#pragma unroll
    for (int r = ty; r < 32; r += 8) {
        float v = W[(size_t)(by + r) * H_DIM + bx + tx];
        Wb[(size_t)(by + r) * H_DIM + bx + tx] = (bf16_t)v;
        tile[r][tx] = v;
    }
    __syncthreads();
#pragma unroll
    for (int r = ty; r < 32; r += 8)
        Wtb[(size_t)(bx + r) * V_DIM + by + tx] = (bf16_t)tile[tx][r];
}

// h1 = tanh(cond @ W1 + b1), one lane per (row, j)
__global__ void h1_kernel(const float* __restrict__ cond, const float* __restrict__ W1,
                          const float* __restrict__ b1, float* __restrict__ h1) {
    int row = blockIdx.x * 4 + (threadIdx.x >> 6);
    int j   = threadIdx.x & 63;
    const float* cr = cond + (size_t)row * C_DIM;
    float s = b1[j];
#pragma unroll 8
    for (int k = 0; k < C_DIM; ++k) s = fmaf(cr[k], W1[k * 64 + j], s);
    h1[(size_t)row * 64 + j] = tanhf(s);
}

// b_mod[i,v] = (1+gamma_b)*b[v] + beta_b ; c_mod[i,h] = (1+gamma_c)*c[h] + beta_c
// gamma/beta come from h1[i] . W2[:, col] + b2[col]; cols per reference slicing.
__global__ void mods_kernel(const float* __restrict__ h1, const float* __restrict__ W2,
                            const float* __restrict__ b2, const float* __restrict__ b,
                            const float* __restrict__ c, float* __restrict__ b_mod,
                            float* __restrict__ c_mod) {
    size_t gid = (size_t)blockIdx.x * 256 + threadIdx.x;   // B * 2048
    int row = (int)(gid >> 11);
    int j   = (int)(gid & 2047);
    const float* h = h1 + (size_t)row * 64;
    int gcol, bcol, dj; const float* baseptr; float* dst;
    if (j < V_DIM) { dj = j;         gcol = dj;                     bcol = V_DIM + dj;             dst = b_mod; baseptr = b; }
    else           { dj = j - V_DIM; gcol = 2 * V_DIM + dj;         bcol = 2 * V_DIM + H_DIM + dj; dst = c_mod; baseptr = c; }
    float g = b2[gcol], be = b2[bcol];
#pragma unroll 8
    for (int k = 0; k < 64; ++k) {
        float hv = h[k];
        g  = fmaf(hv, W2[k * P_COLS + gcol], g);
        be = fmaf(hv, W2[k * P_COLS + bcol], be);
    }
    dst[(size_t)row * 1024 + dj] = (1.0f + g) * baseptr[dj] + be;
}

__global__ void initv_kernel(bf16_t* __restrict__ v, uint32_t tag) {
    uint32_t i = blockIdx.x * 256 + threadIdx.x;
    v[i] = (rng_u01(i, tag) < 0.5f) ? (bf16_t)1.0f : (bf16_t)0.0f;
}

__global__ void cast_kernel(const float* __restrict__ src, bf16_t* __restrict__ dst) {
    size_t i = (size_t)blockIdx.x * 256 + threadIdx.x;
    dst[i] = (bf16_t)src[i];  // 0/1 exact
}

// out += scale * sum((v_model - v_data) * b_mod)
// R1 fix: was 262144 same-address atomics (3.3 ms of serialization @27 GB/s).
// Now: grid-stride + float4/bf16x4 vector loads, wave shuffle-reduce, LDS
// combine, ONE atomicAdd per block (2048 total).
__global__ __launch_bounds__(256) void bdot_kernel(
    const bf16_t* __restrict__ vm, const float* __restrict__ vd,
    const float* __restrict__ bm, float* __restrict__ out, float scale) {
    const size_t n4 = (size_t)B_ROWS * V_DIM / 4;
    const size_t stride = (size_t)gridDim.x * blockDim.x;
    float local = 0.0f;
    for (size_t i4 = (size_t)blockIdx.x * blockDim.x + threadIdx.x; i4 < n4; i4 += stride) {
        f32x4  d = ((const f32x4*)vd)[i4];
        f32x4  m = ((const f32x4*)bm)[i4];
        bf16x4 v = ((const bf16x4*)vm)[i4];
#pragma unroll
        for (int j = 0; j < 4; ++j)
            local += ((float)v[j] - d[j]) * m[j];
    }
    local *= scale;
    for (int off = 32; off > 0; off >>= 1)
        local += __shfl_down(local, off, 64);
    __shared__ float wsum[4];
    int lane = threadIdx.x & 63, wave = threadIdx.x >> 6;
    if (lane == 0) wsum[wave] = local;
    __syncthreads();
    if (threadIdx.x == 0)
        atomicAdd(out, wsum[0] + wsum[1] + wsum[2] + wsum[3]);
}

// ---------------------------------------------------------------------------
extern "C" void kernel_launch(void* const* d_in, const int* in_sizes, int n_in,
                              void* d_out, int out_size, void* d_ws, size_t ws_size,
                              hipStream_t stream) {
    (void)in_sizes; (void)n_in; (void)out_size; (void)ws_size;
    const float* v_data = (const float*)d_in[0];
    const float* cond   = (const float*)d_in[1];
    const float* W      = (const float*)d_in[2];
    const float* b      = (const float*)d_in[3];
    const float* c      = (const float*)d_in[4];
    const float* W1     = (const float*)d_in[5];
    const float* b1     = (const float*)d_in[6];
    const float* W2     = (const float*)d_in[7];
    const float* b2     = (const float*)d_in[8];
    float* out = (float*)d_out;
    char*  ws  = (char*)d_ws;

    const size_t MB = 1024 * 1024;
    bf16_t* Wb    = (bf16_t*)(ws + 0 * MB);    //  2 MB  bf16 W   (VxH)
    bf16_t* Wtb   = (bf16_t*)(ws + 2 * MB);    //  2 MB  bf16 W^T (HxV)
    float*  h1    = (float*) (ws + 4 * MB);    //  4 MB  tanh(cond@W1+b1)
    float*  b_mod = (float*) (ws + 8 * MB);    // 64 MB  (B x V) fp32
    float*  c_mod = (float*) (ws + 72 * MB);   // 64 MB  (B x H) fp32
    bf16_t* vbuf  = (bf16_t*)(ws + 136 * MB);  // 32 MB  (B x V) bf16
    bf16_t* hbuf  = (bf16_t*)(ws + 168 * MB);  // 32 MB  (B x H) bf16 (+v_data cast)
    // total 200 MB

    hipMemsetAsync(d_out, 0, sizeof(float), stream);

    wconv_kernel<<<dim3(32, 32), 256, 0, stream>>>(W, Wb, Wtb);
    h1_kernel<<<B_ROWS / 4, 256, 0, stream>>>(cond, W1, b1, h1);
    mods_kernel<<<(B_ROWS * 2048) / 256, 256, 0, stream>>>(h1, W2, b2, b, c, b_mod, c_mod);
    initv_kernel<<<(B_ROWS * V_DIM) / 256, 256, 0, stream>>>(vbuf, 7u);

    dim3 ggrid(H_DIM / 128, B_ROWS / 128);  // 8 x 128 = 1024 blocks
    const float invB = 1.0f / (float)B_ROWS;

    for (int k = 0; k < K_STEPS; ++k) {
        // h ~ Bern(sigmoid(v @ W + c_mod)) : A=v, Bt=W^T(bf16, HxV)
        gemm_ep<0><<<ggrid, 256, 0, stream>>>(vbuf, Wtb, c_mod, hbuf, nullptr,
                                              B_ROWS, H_DIM, V_DIM,
                                              100u + 2u * (uint32_t)k, 0.0f);
        // v ~ Bern(sigmoid(h @ W^T + b_mod)) : A=h, Bt=W(bf16, VxH)
        gemm_ep<0><<<ggrid, 256, 0, stream>>>(hbuf, Wb, b_mod, vbuf, nullptr,
                                              B_ROWS, V_DIM, H_DIM,
                                              101u + 2u * (uint32_t)k, 0.0f);
    }

    // loss*B = sum softplus(v_model@W + c_mod) - sum softplus(v_data@W + c_mod)
    //          + sum (v_model - v_data)*b_mod
    gemm_ep<1><<<ggrid, 256, 0, stream>>>(vbuf, Wtb, c_mod, nullptr, out,
                                          B_ROWS, H_DIM, V_DIM, 0u, invB);
    cast_kernel<<<(B_ROWS * V_DIM) / 256, 256, 0, stream>>>(v_data, hbuf);
    gemm_ep<1><<<ggrid, 256, 0, stream>>>(hbuf, Wtb, c_mod, nullptr, out,
                                          B_ROWS, H_DIM, V_DIM, 1u, -invB);
    bdot_kernel<<<2048, 256, 0, stream>>>(vbuf, v_data, b_mod, out, invB);
}

// Round 3
// 3687.267 us; speedup vs baseline: 2.0982x; 1.1247x over previous
//
#include <hip/hip_runtime.h>
#include <stdint.h>

// Problem constants (match reference)
#define B_ROWS 16384
#define V_DIM  1024
#define H_DIM  1024
#define KA     1088   // augmented K = V_DIM + 64 (h1 folded into GEMM)
#define C_DIM  64
#define P_COLS 4096   // 2*(V+H)
#define K_STEPS 25

typedef __bf16 bf16_t;
typedef bf16_t bf16x8 __attribute__((ext_vector_type(8)));
typedef bf16_t bf16x4 __attribute__((ext_vector_type(4)));
typedef float  f32x4  __attribute__((ext_vector_type(4)));

// ---------------------------------------------------------------------------
// Counter-based RNG: lowbias32-style hash. Unbiased uniform in [0,1).
// Distribution matches jax.random in law; mean-over-16384-chains loss is
// RNG-implementation-invariant (R1/R2: absmax 0.0 vs tol 15.28).
// ---------------------------------------------------------------------------
__device__ __forceinline__ float rng_u01(uint32_t idx, uint32_t tag) {
    uint32_t x = idx * 0x9E3779B9u ^ (tag * 0x85EBCA6Bu + 0xC2B2AE35u);
    x ^= x >> 16; x *= 0x7FEB352Du;
    x ^= x >> 15; x *= 0x846CA68Bu;
    x ^= x >> 16;
    return (float)(x >> 8) * 5.9604644775390625e-8f; // /2^24
}

// async global->LDS, 16B per lane. LDS dst = wave-uniform base + lane*16.
__device__ __forceinline__ void load_lds16(const void* g, void* l) {
    __builtin_amdgcn_global_load_lds(
        (__attribute__((address_space(1))) void*)(uintptr_t)(g),
        (__attribute__((address_space(3))) void*)(l),
        16, 0, 0);
}

__device__ __forceinline__ float softplus_f(float x) {
    return fmaxf(x, 0.0f) + log1pf(__expf(-fabsf(x)));
}

// ---------------------------------------------------------------------------
// GEMM C = A (MxK) * Bt^T (Bt is NxK row-major), K = KA = 1088 (mod folded in:
// A = [state | h1], Bt = [W-part | What-part]). Epilogue adds per-column
// constant cvec[col] (the row-independent part of the modulation).
// MODE 0: out = bernoulli(sigmoid(C + cvec)) as bf16, stride-K rows
// MODE 1: atomicAdd(out_scalar, scale * sum(softplus(C + cvec)))
// 128x128 tile, BK=32, 4 waves, each wave 64x64 via 4x4 mfma_f32_16x16x32_bf16
// ---------------------------------------------------------------------------
template <int MODE>
__global__ __launch_bounds__(256, 2) void gemm_ep(
    const bf16_t* __restrict__ A, const bf16_t* __restrict__ Bt,
    const float* __restrict__ cvec, bf16_t* __restrict__ out_s,
    float* __restrict__ out_scalar, int M, int N, int K,
    uint32_t tag, float scale)
{
    constexpr int BM = 128, BN = 128, BK = 32;
    __shared__ __align__(16) bf16_t sA[BM * BK];
    __shared__ __align__(16) bf16_t sB[BN * BK];

    const int tid  = threadIdx.x;
    const int wave = tid >> 6;
    const int lane = tid & 63;
    const int m0 = blockIdx.y * BM;
    const int n0 = blockIdx.x * BN;
    const int wr = (wave >> 1) * 64;   // wave's row offset in tile
    const int wc = (wave & 1) * 64;    // wave's col offset in tile
    const int cl   = lane & 15;
    const int quad = lane >> 4;

    // staging: each wave loads 32 rows of A-tile and 32 rows of Bt-tile.
    // one 16B/lane wave-load covers 16 rows (row = 32 elems = 4 lanes).
    const int srow = wave * 32 + (lane >> 2);
    const int skc  = (lane & 3) * 8;
    const bf16_t* gA0 = A  + (size_t)(m0 + srow) * K + skc;
    const bf16_t* gA1 = gA0 + (size_t)16 * K;
    const bf16_t* gB0 = Bt + (size_t)(n0 + srow) * K + skc;
    const bf16_t* gB1 = gB0 + (size_t)16 * K;
    bf16_t* lA0 = sA + (wave * 32) * BK;
    bf16_t* lA1 = sA + (wave * 32 + 16) * BK;
    bf16_t* lB0 = sB + (wave * 32) * BK;
    bf16_t* lB1 = sB + (wave * 32 + 16) * BK;

    f32x4 acc[4][4] = {};

    for (int kt = 0; kt < K; kt += BK) {
        load_lds16(gA0 + kt, lA0);
        load_lds16(gA1 + kt, lA1);
        load_lds16(gB0 + kt, lB0);
        load_lds16(gB1 + kt, lB1);
        __syncthreads();   // drains vmcnt before barrier (compiler-inserted)

        bf16x8 af[4], bfr[4];
#pragma unroll
        for (int mi = 0; mi < 4; ++mi)
            af[mi] = *(const bf16x8*)(sA + (wr + mi * 16 + cl) * BK + quad * 8);
#pragma unroll
        for (int ni = 0; ni < 4; ++ni)
            bfr[ni] = *(const bf16x8*)(sB + (wc + ni * 16 + cl) * BK + quad * 8);
#pragma unroll
        for (int mi = 0; mi < 4; ++mi)
#pragma unroll
            for (int ni = 0; ni < 4; ++ni)
                acc[mi][ni] = __builtin_amdgcn_mfma_f32_16x16x32_bf16(
                    af[mi], bfr[ni], acc[mi][ni], 0, 0, 0);
        __syncthreads();
    }

    // Epilogue. C/D layout: col = lane&15, row = quad*4 + reg  [m89/m91]
    const int row_base = m0 + wr + quad * 4;
    const int col_base = n0 + wc + cl;

    float cv[4];
#pragma unroll
    for (int ni = 0; ni < 4; ++ni) cv[ni] = cvec[col_base + ni * 16];

    if (MODE == 0) {
#pragma unroll
        for (int mi = 0; mi < 4; ++mi) {
#pragma unroll
            for (int ni = 0; ni < 4; ++ni) {
#pragma unroll
                for (int r = 0; r < 4; ++r) {
                    int row = row_base + mi * 16 + r;
                    int col = col_base + ni * 16;
                    size_t o = (size_t)row * K + col;   // stride KA rows
                    float x = acc[mi][ni][r] + cv[ni];
                    float p = 1.0f / (1.0f + __expf(-x));
                    float u = rng_u01((uint32_t)o, tag);
                    out_s[o] = (u < p) ? (bf16_t)1.0f : (bf16_t)0.0f;
                }
            }
        }
    } else {
        float local = 0.0f;
#pragma unroll
        for (int mi = 0; mi < 4; ++mi) {
#pragma unroll
            for (int ni = 0; ni < 4; ++ni) {
#pragma unroll
                for (int r = 0; r < 4; ++r) {
                    local += softplus_f(acc[mi][ni][r] + cv[ni]);
                }
            }
        }
        local *= scale;
        for (int off = 32; off > 0; off >>= 1)
            local += __shfl_down(local, off, 64);
        __shared__ float wsum[4];
        if (lane == 0) wsum[wave] = local;
        __syncthreads();
        if (tid == 0)
            atomicAdd(out_scalar, wsum[0] + wsum[1] + wsum[2] + wsum[3]);
    }
}

// ---------------------------------------------------------------------------
// W (VxH fp32, rows=v cols=h) -> main parts of the two B-operands (bf16):
//   Btv[n][k] = W[n][k]     (v-GEMM: x[i,n] = sum_k h[i,k] W[n,k])
//   Bth[n][k] = W[k][n]     (h-GEMM: x[i,n] = sum_k v[i,k] W[k,n])
// Both have row stride KA = 1088 (last 64 cols filled by wtail_kernel).
// ---------------------------------------------------------------------------
__global__ void wpack_kernel(const float* __restrict__ W,
                             bf16_t* __restrict__ Btv, bf16_t* __restrict__ Bth) {
    __shared__ float tile[32][33];
    int bx = blockIdx.x * 32, by = blockIdx.y * 32;
    int tx = threadIdx.x & 31, ty = threadIdx.x >> 5;
#pragma unroll
    for (int r = ty; r < 32; r += 8) {
        float v = W[(size_t)(by + r) * H_DIM + bx + tx];
        Btv[(size_t)(by + r) * KA + bx + tx] = (bf16_t)v;
        tile[r][tx] = v;
    }
    __syncthreads();
#pragma unroll
    for (int r = ty; r < 32; r += 8)
        Bth[(size_t)(bx + r) * KA + by + tx] = (bf16_t)tile[tx][r];
}

// Tail columns [1024,1088) of Btv/Bth: the rank-64 modulation factors.
//   Bth[n][1024+k'] = Whc[k'][n] = W2[k', 2V+n]*c[n] + W2[k', 2V+H+n]
//   Btv[n][1024+k'] = Whb[k'][n] = W2[k', n]*b[n]    + W2[k', V+n]
__global__ void wtail_kernel(const float* __restrict__ W2, const float* __restrict__ b,
                             const float* __restrict__ c,
                             bf16_t* __restrict__ Btv, bf16_t* __restrict__ Bth) {
    int gid = blockIdx.x * 256 + threadIdx.x;   // 1024*64
    int n = gid >> 6, kp = gid & 63;
    float wc = W2[(size_t)kp * P_COLS + 2048 + n] * c[n] + W2[(size_t)kp * P_COLS + 3072 + n];
    float wb = W2[(size_t)kp * P_COLS + n] * b[n]        + W2[(size_t)kp * P_COLS + 1024 + n];
    Bth[(size_t)n * KA + 1024 + kp] = (bf16_t)wc;
    Btv[(size_t)n * KA + 1024 + kp] = (bf16_t)wb;
}

// Row-independent modulation constants:
//   bhat[n] = b[n]*(1+b2[n])      + b2[V+n]
//   chat[n] = c[n]*(1+b2[2V+n])   + b2[2V+H+n]
__global__ void hatvec_kernel(const float* __restrict__ b, const float* __restrict__ c,
                              const float* __restrict__ b2,
                              float* __restrict__ bhat, float* __restrict__ chat) {
    int n = blockIdx.x * 256 + threadIdx.x;
    bhat[n] = b[n] * (1.0f + b2[n]) + b2[1024 + n];
    chat[n] = c[n] * (1.0f + b2[2048 + n]) + b2[3072 + n];
}

// h1 = tanh(cond @ W1 + b1); writes fp32 h1f (B x 64) and bf16 copies into
// the tail columns [1024,1088) of vbuf, hbuf, vdbuf (stride KA).
__global__ void h1_kernel(const float* __restrict__ cond, const float* __restrict__ W1,
                          const float* __restrict__ b1, float* __restrict__ h1f,
                          bf16_t* __restrict__ vbuf, bf16_t* __restrict__ hbuf,
                          bf16_t* __restrict__ vdbuf) {
    int row = blockIdx.x * 4 + (threadIdx.x >> 6);
    int j   = threadIdx.x & 63;
    const float* cr = cond + (size_t)row * C_DIM;
    float s = b1[j];
#pragma unroll 8
    for (int k = 0; k < C_DIM; ++k) s = fmaf(cr[k], W1[k * 64 + j], s);
    float t = tanhf(s);
    h1f[(size_t)row * 64 + j] = t;
    size_t o = (size_t)row * KA + 1024 + j;
    bf16_t tb = (bf16_t)t;
    vbuf[o] = tb; hbuf[o] = tb; vdbuf[o] = tb;
}

// v_start ~ Bern(0.5) into vbuf cols [0,1024), stride KA
__global__ void initv_kernel(bf16_t* __restrict__ v, uint32_t tag) {
    uint32_t i = blockIdx.x * 256 + threadIdx.x;
    uint32_t row = i >> 10, col = i & 1023;
    v[(size_t)row * KA + col] = (rng_u01(i, tag) < 0.5f) ? (bf16_t)1.0f : (bf16_t)0.0f;
}

// v_data (fp32, 0/1) -> vdbuf cols [0,1024), stride KA (bf16 exact)
__global__ void cast_kernel(const float* __restrict__ src, bf16_t* __restrict__ dst) {
    uint32_t i = blockIdx.x * 256 + threadIdx.x;
    uint32_t row = i >> 10, col = i & 1023;
    dst[(size_t)row * KA + col] = (bf16_t)src[(size_t)row * 1024 + col];
}

// out += scale * sum_ij (vm - vd)_ij * b_mod_ij, with b_mod recomputed on the
// fly from the rank-64 factorization: b_mod[i,j] = bhat[j] + h1[i,:].Whb[:,j].
// Whb^T[j][k] lives in the Btv tail (bf16, contiguous 64 per column j).
// Block = 8 rows x 1024 cols; h1 rows staged in LDS (broadcast reads).
__global__ __launch_bounds__(256) void bdot_kernel(
    const bf16_t* __restrict__ vm, const bf16_t* __restrict__ vd,
    const bf16_t* __restrict__ Btv, const float* __restrict__ bhat,
    const float* __restrict__ h1f, float* __restrict__ out, float scale) {
    __shared__ float sh1[8 * 64];
    int r0 = blockIdx.x * 8;
    for (int t = threadIdx.x; t < 512; t += 256)
        sh1[t] = h1f[(size_t)r0 * 64 + t];
    __syncthreads();

    float local = 0.0f;
    for (int s = 0; s < 4; ++s) {
        int j = s * 256 + threadIdx.x;   // coalesced vm/vd access
        float w[64];
        const bf16x8* wp = (const bf16x8*)(Btv + (size_t)j * KA + 1024);
#pragma unroll
        for (int q = 0; q < 8; ++q) {
            bf16x8 v8 = wp[q];
#pragma unroll
            for (int e = 0; e < 8; ++e) w[q * 8 + e] = (float)v8[e];
        }
        float bj = bhat[j];
#pragma unroll
        for (int r = 0; r < 8; ++r) {
            float d = (float)vm[(size_t)(r0 + r) * KA + j]
                    - (float)vd[(size_t)(r0 + r) * KA + j];
            if (d != 0.0f) {
                float bm = bj;
#pragma unroll
                for (int k = 0; k < 64; ++k) bm = fmaf(sh1[r * 64 + k], w[k], bm);
                local += d * bm;
            }
        }
    }
    local *= scale;
    for (int off = 32; off > 0; off >>= 1)
        local += __shfl_down(local, off, 64);
    __shared__ float wsum[4];
    int lane = threadIdx.x & 63, wave = threadIdx.x >> 6;
    if (lane == 0) wsum[wave] = local;
    __syncthreads();
    if (threadIdx.x == 0)
        atomicAdd(out, wsum[0] + wsum[1] + wsum[2] + wsum[3]);
}

// ---------------------------------------------------------------------------
extern "C" void kernel_launch(void* const* d_in, const int* in_sizes, int n_in,
                              void* d_out, int out_size, void* d_ws, size_t ws_size,
                              hipStream_t stream) {
    (void)in_sizes; (void)n_in; (void)out_size; (void)ws_size;
    const float* v_data = (const float*)d_in[0];
    const float* cond   = (const float*)d_in[1];
    const float* W      = (const float*)d_in[2];
    const float* b      = (const float*)d_in[3];
    const float* c      = (const float*)d_in[4];
    const float* W1     = (const float*)d_in[5];
    const float* b1     = (const float*)d_in[6];
    const float* W2     = (const float*)d_in[7];
    const float* b2     = (const float*)d_in[8];
    float* out = (float*)d_out;
    char*  ws  = (char*)d_ws;

    const size_t MB = 1024 * 1024;
    bf16_t* Btv  = (bf16_t*)(ws + 0 * MB);    // 1024 x 1088 bf16 (~2.2 MB)
    bf16_t* Bth  = (bf16_t*)(ws + 4 * MB);    // 1024 x 1088 bf16
    float*  h1f  = (float*) (ws + 8 * MB);    // B x 64 fp32 (4 MB)
    float*  bhat = (float*) (ws + 12 * MB);   // 4 KB
    float*  chat = (float*) (ws + 13 * MB);   // 4 KB
    bf16_t* vbuf = (bf16_t*)(ws + 16 * MB);   // B x 1088 bf16 (34 MB)
    bf16_t* hbuf = (bf16_t*)(ws + 52 * MB);   // B x 1088 bf16
    bf16_t* vdbuf= (bf16_t*)(ws + 88 * MB);   // B x 1088 bf16
    // total ~124 MB

    hipMemsetAsync(d_out, 0, sizeof(float), stream);

    h1_kernel<<<B_ROWS / 4, 256, 0, stream>>>(cond, W1, b1, h1f, vbuf, hbuf, vdbuf);
    wpack_kernel<<<dim3(32, 32), 256, 0, stream>>>(W, Btv, Bth);
    wtail_kernel<<<(1024 * 64) / 256, 256, 0, stream>>>(W2, b, c, Btv, Bth);
    hatvec_kernel<<<4, 256, 0, stream>>>(b, c, b2, bhat, chat);
    initv_kernel<<<(B_ROWS * 1024) / 256, 256, 0, stream>>>(vbuf, 7u);
    cast_kernel<<<(B_ROWS * 1024) / 256, 256, 0, stream>>>(v_data, vdbuf);

    dim3 ggrid(1024 / 128, B_ROWS / 128);  // 8 x 128 = 1024 blocks
    const float invB = 1.0f / (float)B_ROWS;

    for (int k = 0; k < K_STEPS; ++k) {
        // h ~ Bern(sigmoid(v@W + c_mod)) : A=[v|h1], Bt=[W^T|Whc^T], +chat
        gemm_ep<0><<<ggrid, 256, 0, stream>>>(vbuf, Bth, chat, hbuf, nullptr,
                                              B_ROWS, H_DIM, KA,
                                              100u + 2u * (uint32_t)k, 0.0f);
        // v ~ Bern(sigmoid(h@W + b_mod)) : A=[h|h1], Bt=[W|Whb^T], +bhat
        gemm_ep<0><<<ggrid, 256, 0, stream>>>(hbuf, Btv, bhat, vbuf, nullptr,
                                              B_ROWS, V_DIM, KA,
                                              101u + 2u * (uint32_t)k, 0.0f);
    }

    // loss*B = sum softplus(v_model@W + c_mod) - sum softplus(v_data@W + c_mod)
    //          + sum (v_model - v_data)*b_mod
    gemm_ep<1><<<ggrid, 256, 0, stream>>>(vbuf, Bth, chat, nullptr, out,
                                          B_ROWS, H_DIM, KA, 0u, invB);
    gemm_ep<1><<<ggrid, 256, 0, stream>>>(vdbuf, Bth, chat, nullptr, out,
                                          B_ROWS, H_DIM, KA, 1u, -invB);
    bdot_kernel<<<B_ROWS / 8, 256, 0, stream>>>(vbuf, vdbuf, Btv, bhat, h1f, out, invB);
}

// Round 4
// 3513.120 us; speedup vs baseline: 2.2022x; 1.0496x over previous
//
#include <hip/hip_runtime.h>
#include <stdint.h>

// Problem constants (match reference)
#define B_ROWS 16384
#define V_DIM  1024
#define H_DIM  1024
#define KA     1088   // augmented K = V_DIM + 64 (h1 folded into GEMM)
#define C_DIM  64
#define P_COLS 4096   // 2*(V+H)
#define K_STEPS 25

typedef __bf16 bf16_t;
typedef bf16_t bf16x8 __attribute__((ext_vector_type(8)));
typedef bf16_t bf16x4 __attribute__((ext_vector_type(4)));
typedef float  f32x4  __attribute__((ext_vector_type(4)));

// ---------------------------------------------------------------------------
// Counter-based RNG: lowbias32-style hash. Unbiased uniform in [0,1).
// Distribution matches jax.random in law; mean-over-16384-chains loss is
// RNG-implementation-invariant (R1/R2/R3: absmax 0.0 vs tol 15.28).
// ---------------------------------------------------------------------------
__device__ __forceinline__ float rng_u01(uint32_t idx, uint32_t tag) {
    uint32_t x = idx * 0x9E3779B9u ^ (tag * 0x85EBCA6Bu + 0xC2B2AE35u);
    x ^= x >> 16; x *= 0x7FEB352Du;
    x ^= x >> 15; x *= 0x846CA68Bu;
    x ^= x >> 16;
    return (float)(x >> 8) * 5.9604644775390625e-8f; // /2^24
}

// async global->LDS, 16B per lane. LDS dst = wave-uniform base + lane*16.
__device__ __forceinline__ void load_lds16(const void* g, void* l) {
    __builtin_amdgcn_global_load_lds(
        (__attribute__((address_space(1))) void*)(uintptr_t)(g),
        (__attribute__((address_space(3))) void*)(l),
        16, 0, 0);
}

__device__ __forceinline__ float softplus_f(float x) {
    return fmaxf(x, 0.0f) + log1pf(__expf(-fabsf(x)));
}

// ---------------------------------------------------------------------------
// GEMM C = A (MxK) * Bt^T (Bt is NxK row-major), K = KA = 1088 (mod folded in:
// A = [state | h1], Bt = [W-part | What-part]). Epilogue adds per-column
// constant cvec[col] (the row-independent part of the modulation).
// MODE 0: out = bernoulli(sigmoid(C + cvec)) as bf16, stride-K rows
// MODE 1: atomicAdd(out_scalar, scale * sum(softplus(C + cvec)))
// 128x128 tile, BK=32, 4 waves, each wave 64x64 via 4x4 mfma_f32_16x16x32_bf16
// ---------------------------------------------------------------------------
template <int MODE>
__global__ __launch_bounds__(256, 2) void gemm_ep(
    const bf16_t* __restrict__ A, const bf16_t* __restrict__ Bt,
    const float* __restrict__ cvec, bf16_t* __restrict__ out_s,
    float* __restrict__ out_scalar, int M, int N, int K,
    uint32_t tag, float scale)
{
    constexpr int BM = 128, BN = 128, BK = 32;
    __shared__ __align__(16) bf16_t sA[BM * BK];
    __shared__ __align__(16) bf16_t sB[BN * BK];

    const int tid  = threadIdx.x;
    const int wave = tid >> 6;
    const int lane = tid & 63;
    const int m0 = blockIdx.y * BM;
    const int n0 = blockIdx.x * BN;
    const int wr = (wave >> 1) * 64;   // wave's row offset in tile
    const int wc = (wave & 1) * 64;    // wave's col offset in tile
    const int cl   = lane & 15;
    const int quad = lane >> 4;

    // staging: each wave loads 32 rows of A-tile and 32 rows of Bt-tile.
    // one 16B/lane wave-load covers 16 rows (row = 32 elems = 4 lanes).
    const int srow = wave * 32 + (lane >> 2);
    const int skc  = (lane & 3) * 8;
    const bf16_t* gA0 = A  + (size_t)(m0 + srow) * K + skc;
    const bf16_t* gA1 = gA0 + (size_t)16 * K;
    const bf16_t* gB0 = Bt + (size_t)(n0 + srow) * K + skc;
    const bf16_t* gB1 = gB0 + (size_t)16 * K;
    bf16_t* lA0 = sA + (wave * 32) * BK;
    bf16_t* lA1 = sA + (wave * 32 + 16) * BK;
    bf16_t* lB0 = sB + (wave * 32) * BK;
    bf16_t* lB1 = sB + (wave * 32 + 16) * BK;

    f32x4 acc[4][4] = {};

    for (int kt = 0; kt < K; kt += BK) {
        load_lds16(gA0 + kt, lA0);
        load_lds16(gA1 + kt, lA1);
        load_lds16(gB0 + kt, lB0);
        load_lds16(gB1 + kt, lB1);
        __syncthreads();   // drains vmcnt before barrier (compiler-inserted)

        bf16x8 af[4], bfr[4];
#pragma unroll
        for (int mi = 0; mi < 4; ++mi)
            af[mi] = *(const bf16x8*)(sA + (wr + mi * 16 + cl) * BK + quad * 8);
#pragma unroll
        for (int ni = 0; ni < 4; ++ni)
            bfr[ni] = *(const bf16x8*)(sB + (wc + ni * 16 + cl) * BK + quad * 8);
#pragma unroll
        for (int mi = 0; mi < 4; ++mi)
#pragma unroll
            for (int ni = 0; ni < 4; ++ni)
                acc[mi][ni] = __builtin_amdgcn_mfma_f32_16x16x32_bf16(
                    af[mi], bfr[ni], acc[mi][ni], 0, 0, 0);
        __syncthreads();
    }

    // Epilogue. C/D layout: col = lane&15, row = quad*4 + reg  [m89/m91]
    const int row_base = m0 + wr + quad * 4;
    const int col_base = n0 + wc + cl;

    float cv[4];
#pragma unroll
    for (int ni = 0; ni < 4; ++ni) cv[ni] = cvec[col_base + ni * 16];

    if (MODE == 0) {
#pragma unroll
        for (int mi = 0; mi < 4; ++mi) {
#pragma unroll
            for (int ni = 0; ni < 4; ++ni) {
#pragma unroll
                for (int r = 0; r < 4; ++r) {
                    int row = row_base + mi * 16 + r;
                    int col = col_base + ni * 16;
                    size_t o = (size_t)row * K + col;   // stride KA rows
                    float x = acc[mi][ni][r] + cv[ni];
                    float p = 1.0f / (1.0f + __expf(-x));
                    float u = rng_u01((uint32_t)o, tag);
                    out_s[o] = (u < p) ? (bf16_t)1.0f : (bf16_t)0.0f;
                }
            }
        }
    } else {
        float local = 0.0f;
#pragma unroll
        for (int mi = 0; mi < 4; ++mi) {
#pragma unroll
            for (int ni = 0; ni < 4; ++ni) {
#pragma unroll
                for (int r = 0; r < 4; ++r) {
                    local += softplus_f(acc[mi][ni][r] + cv[ni]);
                }
            }
        }
        local *= scale;
        for (int off = 32; off > 0; off >>= 1)
            local += __shfl_down(local, off, 64);
        __shared__ float wsum[4];
        if (lane == 0) wsum[wave] = local;
        __syncthreads();
        if (tid == 0)
            atomicAdd(out_scalar, wsum[0] + wsum[1] + wsum[2] + wsum[3]);
    }
}

// ---------------------------------------------------------------------------
// W (VxH fp32, rows=v cols=h) -> main parts of the two B-operands (bf16):
//   Btv[n][k] = W[n][k]     (v-GEMM: x[i,n] = sum_k h[i,k] W[n,k])
//   Bth[n][k] = W[k][n]     (h-GEMM: x[i,n] = sum_k v[i,k] W[k,n])
// Both have row stride KA = 1088 (last 64 cols filled by wtail_kernel).
// ---------------------------------------------------------------------------
__global__ void wpack_kernel(const float* __restrict__ W,
                             bf16_t* __restrict__ Btv, bf16_t* __restrict__ Bth) {
    __shared__ float tile[32][33];
    int bx = blockIdx.x * 32, by = blockIdx.y * 32;
    int tx = threadIdx.x & 31, ty = threadIdx.x >> 5;
#pragma unroll
    for (int r = ty; r < 32; r += 8) {
        float v = W[(size_t)(by + r) * H_DIM + bx + tx];
        Btv[(size_t)(by + r) * KA + bx + tx] = (bf16_t)v;
        tile[r][tx] = v;
    }
    __syncthreads();
#pragma unroll
    for (int r = ty; r < 32; r += 8)
        Bth[(size_t)(bx + r) * KA + by + tx] = (bf16_t)tile[tx][r];
}

// Tail columns [1024,1088) of Btv/Bth: the rank-64 modulation factors.
//   Bth[n][1024+k'] = Whc[k'][n] = W2[k', 2V+n]*c[n] + W2[k', 2V+H+n]
//   Btv[n][1024+k'] = Whb[k'][n] = W2[k', n]*b[n]    + W2[k', V+n]
__global__ void wtail_kernel(const float* __restrict__ W2, const float* __restrict__ b,
                             const float* __restrict__ c,
                             bf16_t* __restrict__ Btv, bf16_t* __restrict__ Bth) {
    int gid = blockIdx.x * 256 + threadIdx.x;   // 1024*64
    int n = gid >> 6, kp = gid & 63;
    float wc = W2[(size_t)kp * P_COLS + 2048 + n] * c[n] + W2[(size_t)kp * P_COLS + 3072 + n];
    float wb = W2[(size_t)kp * P_COLS + n] * b[n]        + W2[(size_t)kp * P_COLS + 1024 + n];
    Bth[(size_t)n * KA + 1024 + kp] = (bf16_t)wc;
    Btv[(size_t)n * KA + 1024 + kp] = (bf16_t)wb;
}

// Row-independent modulation constants:
//   bhat[n] = b[n]*(1+b2[n])      + b2[V+n]
//   chat[n] = c[n]*(1+b2[2V+n])   + b2[2V+H+n]
__global__ void hatvec_kernel(const float* __restrict__ b, const float* __restrict__ c,
                              const float* __restrict__ b2,
                              float* __restrict__ bhat, float* __restrict__ chat) {
    int n = blockIdx.x * 256 + threadIdx.x;
    bhat[n] = b[n] * (1.0f + b2[n]) + b2[1024 + n];
    chat[n] = c[n] * (1.0f + b2[2048 + n]) + b2[3072 + n];
}

// h1 = tanh(cond @ W1 + b1); writes fp32 h1f (B x 64) and bf16 copies into
// the tail columns [1024,1088) of vbuf, hbuf, vdbuf (stride KA).
__global__ void h1_kernel(const float* __restrict__ cond, const float* __restrict__ W1,
                          const float* __restrict__ b1, float* __restrict__ h1f,
                          bf16_t* __restrict__ vbuf, bf16_t* __restrict__ hbuf,
                          bf16_t* __restrict__ vdbuf) {
    int row = blockIdx.x * 4 + (threadIdx.x >> 6);
    int j   = threadIdx.x & 63;
    const float* cr = cond + (size_t)row * C_DIM;
    float s = b1[j];
#pragma unroll 8
    for (int k = 0; k < C_DIM; ++k) s = fmaf(cr[k], W1[k * 64 + j], s);
    float t = tanhf(s);
    h1f[(size_t)row * 64 + j] = t;
    size_t o = (size_t)row * KA + 1024 + j;
    bf16_t tb = (bf16_t)t;
    vbuf[o] = tb; hbuf[o] = tb; vdbuf[o] = tb;
}

// v_start ~ Bern(0.5) into vbuf cols [0,1024), stride KA
__global__ void initv_kernel(bf16_t* __restrict__ v, uint32_t tag) {
    uint32_t i = blockIdx.x * 256 + threadIdx.x;
    uint32_t row = i >> 10, col = i & 1023;
    v[(size_t)row * KA + col] = (rng_u01(i, tag) < 0.5f) ? (bf16_t)1.0f : (bf16_t)0.0f;
}

// v_data (fp32, 0/1) -> vdbuf cols [0,1024), stride KA (bf16 exact)
__global__ void cast_kernel(const float* __restrict__ src, bf16_t* __restrict__ dst) {
    uint32_t i = blockIdx.x * 256 + threadIdx.x;
    uint32_t row = i >> 10, col = i & 1023;
    dst[(size_t)row * KA + col] = (bf16_t)src[(size_t)row * 1024 + col];
}

// out += scale * sum_ij (vm - vd)_ij * b_mod_ij, with b_mod recomputed on the
// fly from the rank-64 factorization: b_mod[i,j] = bhat[j] + h1[i,:].Whb[:,j].
// R3 post-mortem: per-thread w[64] + sh1 LDS staging + branch => VGPR 256,
// 184 MB scratch spills, 300 us. R4: thread = one column j (grid B/8 x 4),
// w[64] fp32 loaded ONCE, h1 read with wave-UNIFORM global addresses
// (scalarizes to s_load; FMA takes the SGPR operand), no branch, 8 rows.
__global__ __launch_bounds__(256) void bdot_kernel(
    const bf16_t* __restrict__ vm, const bf16_t* __restrict__ vd,
    const bf16_t* __restrict__ Btv, const float* __restrict__ bhat,
    const float* __restrict__ h1f, float* __restrict__ out, float scale) {
    const int r0 = (blockIdx.x >> 2) * 8;
    const int j  = (blockIdx.x & 3) * 256 + threadIdx.x;

    float w[64];
    const bf16x8* wp = (const bf16x8*)(Btv + (size_t)j * KA + 1024);
#pragma unroll
    for (int q = 0; q < 8; ++q) {
        bf16x8 v8 = wp[q];
#pragma unroll
        for (int e = 0; e < 8; ++e) w[q * 8 + e] = (float)v8[e];
    }
    const float bj = bhat[j];

    float local = 0.0f;
#pragma unroll 2
    for (int r = 0; r < 8; ++r) {
        const float* h1r = h1f + (size_t)(r0 + r) * 64;  // uniform address
        float bm = bj;
#pragma unroll
        for (int k = 0; k < 64; ++k) bm = fmaf(h1r[k], w[k], bm);
        float d = (float)vm[(size_t)(r0 + r) * KA + j]
                - (float)vd[(size_t)(r0 + r) * KA + j];
        local = fmaf(d, bm, local);
    }
    local *= scale;
    for (int off = 32; off > 0; off >>= 1)
        local += __shfl_down(local, off, 64);
    __shared__ float wsum[4];
    int lane = threadIdx.x & 63, wave = threadIdx.x >> 6;
    if (lane == 0) wsum[wave] = local;
    __syncthreads();
    if (threadIdx.x == 0)
        atomicAdd(out, wsum[0] + wsum[1] + wsum[2] + wsum[3]);
}

// ---------------------------------------------------------------------------
extern "C" void kernel_launch(void* const* d_in, const int* in_sizes, int n_in,
                              void* d_out, int out_size, void* d_ws, size_t ws_size,
                              hipStream_t stream) {
    (void)in_sizes; (void)n_in; (void)out_size; (void)ws_size;
    const float* v_data = (const float*)d_in[0];
    const float* cond   = (const float*)d_in[1];
    const float* W      = (const float*)d_in[2];
    const float* b      = (const float*)d_in[3];
    const float* c      = (const float*)d_in[4];
    const float* W1     = (const float*)d_in[5];
    const float* b1     = (const float*)d_in[6];
    const float* W2     = (const float*)d_in[7];
    const float* b2     = (const float*)d_in[8];
    float* out = (float*)d_out;
    char*  ws  = (char*)d_ws;

    const size_t MB = 1024 * 1024;
    bf16_t* Btv  = (bf16_t*)(ws + 0 * MB);    // 1024 x 1088 bf16 (~2.2 MB)
    bf16_t* Bth  = (bf16_t*)(ws + 4 * MB);    // 1024 x 1088 bf16
    float*  h1f  = (float*) (ws + 8 * MB);    // B x 64 fp32 (4 MB)
    float*  bhat = (float*) (ws + 12 * MB);   // 4 KB
    float*  chat = (float*) (ws + 13 * MB);   // 4 KB
    bf16_t* vbuf = (bf16_t*)(ws + 16 * MB);   // B x 1088 bf16 (34 MB)
    bf16_t* hbuf = (bf16_t*)(ws + 52 * MB);   // B x 1088 bf16
    bf16_t* vdbuf= (bf16_t*)(ws + 88 * MB);   // B x 1088 bf16
    // total ~124 MB

    hipMemsetAsync(d_out, 0, sizeof(float), stream);

    h1_kernel<<<B_ROWS / 4, 256, 0, stream>>>(cond, W1, b1, h1f, vbuf, hbuf, vdbuf);
    wpack_kernel<<<dim3(32, 32), 256, 0, stream>>>(W, Btv, Bth);
    wtail_kernel<<<(1024 * 64) / 256, 256, 0, stream>>>(W2, b, c, Btv, Bth);
    hatvec_kernel<<<4, 256, 0, stream>>>(b, c, b2, bhat, chat);
    initv_kernel<<<(B_ROWS * 1024) / 256, 256, 0, stream>>>(vbuf, 7u);
    cast_kernel<<<(B_ROWS * 1024) / 256, 256, 0, stream>>>(v_data, vdbuf);

    dim3 ggrid(1024 / 128, B_ROWS / 128);  // 8 x 128 = 1024 blocks
    const float invB = 1.0f / (float)B_ROWS;

    for (int k = 0; k < K_STEPS; ++k) {
        // h ~ Bern(sigmoid(v@W + c_mod)) : A=[v|h1], Bt=[W^T|Whc^T], +chat
        gemm_ep<0><<<ggrid, 256, 0, stream>>>(vbuf, Bth, chat, hbuf, nullptr,
                                              B_ROWS, H_DIM, KA,
                                              100u + 2u * (uint32_t)k, 0.0f);
        // v ~ Bern(sigmoid(h@W + b_mod)) : A=[h|h1], Bt=[W|Whb^T], +bhat
        gemm_ep<0><<<ggrid, 256, 0, stream>>>(hbuf, Btv, bhat, vbuf, nullptr,
                                              B_ROWS, V_DIM, KA,
                                              101u + 2u * (uint32_t)k, 0.0f);
    }

    // loss*B = sum softplus(v_model@W + c_mod) - sum softplus(v_data@W + c_mod)
    //          + sum (v_model - v_data)*b_mod
    gemm_ep<1><<<ggrid, 256, 0, stream>>>(vbuf, Bth, chat, nullptr, out,
                                          B_ROWS, H_DIM, KA, 0u, invB);
    gemm_ep<1><<<ggrid, 256, 0, stream>>>(vdbuf, Bth, chat, nullptr, out,
                                          B_ROWS, H_DIM, KA, 1u, -invB);
    bdot_kernel<<<(B_ROWS / 8) * 4, 256, 0, stream>>>(vbuf, vdbuf, Btv, bhat, h1f, out, invB);
}

// Round 5
// 2260.426 us; speedup vs baseline: 3.4226x; 1.5542x over previous
//
#include <hip/hip_runtime.h>
#include <stdint.h>

// Problem constants (match reference)
#define B_ROWS 16384
#define V_DIM  1024
#define H_DIM  1024
#define KB     1152   // padded K: 1024 state + 64 h1-tail + 64 ZERO pad (mult of 128)
#define C_DIM  64
#define P_COLS 4096   // 2*(V+H)
#define K_STEPS 25

#define FP8_ONE 0x38  // e4m3fn 1.0

typedef float f32x4 __attribute__((ext_vector_type(4)));
typedef int   v8i   __attribute__((ext_vector_type(8)));

// ---------------------------------------------------------------------------
// Counter-based RNG: lowbias32-style hash. Unbiased uniform in [0,1).
// Mean-over-16384-chains loss is RNG-implementation-invariant (R1-R4 absmax 0).
// ---------------------------------------------------------------------------
__device__ __forceinline__ float rng_u01(uint32_t idx, uint32_t tag) {
    uint32_t x = idx * 0x9E3779B9u ^ (tag * 0x85EBCA6Bu + 0xC2B2AE35u);
    x ^= x >> 16; x *= 0x7FEB352Du;
    x ^= x >> 15; x *= 0x846CA68Bu;
    x ^= x >> 16;
    return (float)(x >> 8) * 5.9604644775390625e-8f; // /2^24
}

// async global->LDS, 16B per lane. LDS dst = wave-uniform base + lane*16.
__device__ __forceinline__ void load_lds16(const void* g, void* l) {
    __builtin_amdgcn_global_load_lds(
        (__attribute__((address_space(1))) void*)(uintptr_t)(g),
        (__attribute__((address_space(3))) void*)(l),
        16, 0, 0);
}

__device__ __forceinline__ float softplus_f(float x) {
    return fmaxf(x, 0.0f) + log1pf(__expf(-fabsf(x)));
}

// float -> OCP fp8 e4m3 via the HW packed-convert (guarantees MFMA-compatible
// encoding on gfx950; RNE satfinite).
__device__ __forceinline__ uint8_t f2fp8(float x) {
    int p = __builtin_amdgcn_cvt_pk_fp8_f32(x, 0.0f, 0, false);
    return (uint8_t)(p & 0xFF);
}

// ---------------------------------------------------------------------------
// MX-fp8 GEMM C = A (MxK) * Bt^T (Bt NxK row-major, fp8 e4m3), K = KB = 1152.
// mfma_scale_f32_16x16x128_f8f6f4 with unit scales (0x7F bytes) => plain fp8
// matmul at 2x bf16 FLOP rate, 4x fewer MFMA insts (K=128/inst).
// BK=128 => LDS rows are 128 B; fragment reads are 2x16B per lane. To avoid
// 16-way bank conflicts, 16B slots are XOR-swizzled by (row&7) — applied on
// BOTH the staging fetch (per-lane global chunk choice; LDS dst stays
// base+lane*16 per the global_load_lds constraint) and the fragment reads.
// MODE 0: out = bernoulli(sigmoid(C + cvec)) as fp8 {0x00,0x38}
// MODE 1: atomicAdd(out_scalar, scale * sum(softplus(C + cvec)))
// ---------------------------------------------------------------------------
template <int MODE>
__global__ __launch_bounds__(256, 2) void gemm_ep(
    const uint8_t* __restrict__ A, const uint8_t* __restrict__ Bt,
    const float* __restrict__ cvec, uint8_t* __restrict__ out_s,
    float* __restrict__ out_scalar, int M, int N, int K,
    uint32_t tag, float scale)
{
    constexpr int BM = 128, BN = 128, BK = 128;
    __shared__ __align__(16) uint8_t sA[BM * BK];   // 16 KB
    __shared__ __align__(16) uint8_t sB[BN * BK];   // 16 KB

    const int tid  = threadIdx.x;
    const int wave = tid >> 6;
    const int lane = tid & 63;
    const int m0 = blockIdx.y * BM;
    const int n0 = blockIdx.x * BN;
    const int wr = (wave >> 1) * 64;   // wave's row offset in tile
    const int wc = (wave & 1) * 64;    // wave's col offset in tile
    const int cl   = lane & 15;
    const int quad = lane >> 4;

    // Staging: per wave-load, 64 lanes x 16B = 8 rows of 128 B.
    // Wave w, chunk t covers rows w*32 + t*8 + (lane>>3).
    // Swizzle: physical slot (lane&7) holds logical slot (lane&7)^(row&7).
    const int lrow8 = lane >> 3;                       // row within chunk, ==row&7
    const int lcol  = ((lane & 7) ^ lrow8) << 4;       // swizzled source 16B col
    const uint8_t* gA = A  + (size_t)(m0 + wave * 32 + lrow8) * K + lcol;
    const uint8_t* gB = Bt + (size_t)(n0 + wave * 32 + lrow8) * K + lcol;
    uint8_t* lA = sA + wave * 4096;   // + t*1024 (+ lane*16 implicit)
    uint8_t* lB = sB + wave * 4096;

    f32x4 acc[4][4] = {};

    union F8 { int4 h[2]; v8i v; };

    for (int kt = 0; kt < K; kt += BK) {
#pragma unroll
        for (int t = 0; t < 4; ++t) {
            load_lds16(gA + kt + (size_t)t * 8 * K, lA + t * 1024);
            load_lds16(gB + kt + (size_t)t * 8 * K, lB + t * 1024);
        }
        __syncthreads();   // drains vmcnt before barrier (compiler-inserted)

        // Fragments: lane holds A[m=cl][k=quad*32..+32) = logical slots 2q,2q+1
        // of row (wr+mi*16+cl); physical slot = logical ^ (cl&7).
        const int xr = cl & 7;
        const int p0 = ((2 * quad) ^ xr) << 4;
        const int p1 = ((2 * quad + 1) ^ xr) << 4;
        v8i af[4], bfr[4];
#pragma unroll
        for (int mi = 0; mi < 4; ++mi) {
            const uint8_t* rp = sA + (wr + mi * 16 + cl) * BK;
            F8 f; f.h[0] = *(const int4*)(rp + p0); f.h[1] = *(const int4*)(rp + p1);
            af[mi] = f.v;
        }
#pragma unroll
        for (int ni = 0; ni < 4; ++ni) {
            const uint8_t* rp = sB + (wc + ni * 16 + cl) * BK;
            F8 f; f.h[0] = *(const int4*)(rp + p0); f.h[1] = *(const int4*)(rp + p1);
            bfr[ni] = f.v;
        }
#pragma unroll
        for (int mi = 0; mi < 4; ++mi)
#pragma unroll
            for (int ni = 0; ni < 4; ++ni)
                acc[mi][ni] = __builtin_amdgcn_mfma_scale_f32_16x16x128_f8f6f4(
                    af[mi], bfr[ni], acc[mi][ni],
                    0, 0,                       // cbsz=FP8(e4m3), blgp=FP8(e4m3)
                    0, 0x7F7F7F7F,              // opsel_a, scale_a (all bytes=127 => x1)
                    0, 0x7F7F7F7F);             // opsel_b, scale_b
        __syncthreads();
    }

    // Epilogue. C/D layout: col = lane&15, row = quad*4 + reg (shape-determined)
    const int row_base = m0 + wr + quad * 4;
    const int col_base = n0 + wc + cl;

    float cv[4];
#pragma unroll
    for (int ni = 0; ni < 4; ++ni) cv[ni] = cvec[col_base + ni * 16];

    if (MODE == 0) {
#pragma unroll
        for (int mi = 0; mi < 4; ++mi) {
#pragma unroll
            for (int ni = 0; ni < 4; ++ni) {
#pragma unroll
                for (int r = 0; r < 4; ++r) {
                    int row = row_base + mi * 16 + r;
                    int col = col_base + ni * 16;
                    size_t o = (size_t)row * KB + col;
                    float x = acc[mi][ni][r] + cv[ni];
                    float p = 1.0f / (1.0f + __expf(-x));
                    float u = rng_u01((uint32_t)o, tag);
                    out_s[o] = (u < p) ? (uint8_t)FP8_ONE : (uint8_t)0;
                }
            }
        }
    } else {
        float local = 0.0f;
#pragma unroll
        for (int mi = 0; mi < 4; ++mi)
#pragma unroll
            for (int ni = 0; ni < 4; ++ni)
#pragma unroll
                for (int r = 0; r < 4; ++r)
                    local += softplus_f(acc[mi][ni][r] + cv[ni]);
        local *= scale;
        for (int off = 32; off > 0; off >>= 1)
            local += __shfl_down(local, off, 64);
        __shared__ float wsum[4];
        if (lane == 0) wsum[wave] = local;
        __syncthreads();
        if (tid == 0)
            atomicAdd(out_scalar, wsum[0] + wsum[1] + wsum[2] + wsum[3]);
    }
}

// ---------------------------------------------------------------------------
// W (VxH fp32) -> fp8 B-operands:
//   Btv[n][k] = W[n][k]  (v-GEMM)    Bth[n][k] = W[k][n]  (h-GEMM)
// Row stride KB; cols [1024,1152) filled by wtail_kernel.
// ---------------------------------------------------------------------------
__global__ void wpack_kernel(const float* __restrict__ W,
                             uint8_t* __restrict__ Btv, uint8_t* __restrict__ Bth) {
    __shared__ float tile[32][33];
    int bx = blockIdx.x * 32, by = blockIdx.y * 32;
    int tx = threadIdx.x & 31, ty = threadIdx.x >> 5;
#pragma unroll
    for (int r = ty; r < 32; r += 8) {
        float v = W[(size_t)(by + r) * H_DIM + bx + tx];
        Btv[(size_t)(by + r) * KB + bx + tx] = f2fp8(v);
        tile[r][tx] = v;
    }
    __syncthreads();
#pragma unroll
    for (int r = ty; r < 32; r += 8)
        Bth[(size_t)(bx + r) * KB + by + tx] = f2fp8(tile[tx][r]);
}

// Tail cols [1024,1152) of Btv/Bth: rank-64 modulation factors, then zeros.
//   Bth[n][1024+k'] = W2[k',2V+n]*c[n] + W2[k',2V+H+n]   (k' < 64)
//   Btv[n][1024+k'] = W2[k',n]*b[n]    + W2[k',V+n]
// Also writes fp32 Whbf[n][k'] (for bdot). kp in [64,128) writes zero pad.
__global__ void wtail_kernel(const float* __restrict__ W2, const float* __restrict__ b,
                             const float* __restrict__ c,
                             uint8_t* __restrict__ Btv, uint8_t* __restrict__ Bth,
                             float* __restrict__ Whbf) {
    int gid = blockIdx.x * 256 + threadIdx.x;   // 1024 * 128
    int n = gid >> 7, kp = gid & 127;
    if (kp < 64) {
        float wc = W2[(size_t)kp * P_COLS + 2048 + n] * c[n] + W2[(size_t)kp * P_COLS + 3072 + n];
        float wb = W2[(size_t)kp * P_COLS + n] * b[n]        + W2[(size_t)kp * P_COLS + 1024 + n];
        Bth[(size_t)n * KB + 1024 + kp] = f2fp8(wc);
        Btv[(size_t)n * KB + 1024 + kp] = f2fp8(wb);
        Whbf[(size_t)n * 64 + kp] = wb;
    } else {
        Bth[(size_t)n * KB + 1024 + kp] = 0;    // zero pad => A-pad poison annihilated
        Btv[(size_t)n * KB + 1024 + kp] = 0;
    }
}

// Row-independent modulation constants:
//   bhat[n] = b[n]*(1+b2[n]) + b2[V+n] ; chat[n] = c[n]*(1+b2[2V+n]) + b2[2V+H+n]
__global__ void hatvec_kernel(const float* __restrict__ b, const float* __restrict__ c,
                              const float* __restrict__ b2,
                              float* __restrict__ bhat, float* __restrict__ chat) {
    int n = blockIdx.x * 256 + threadIdx.x;
    bhat[n] = b[n] * (1.0f + b2[n]) + b2[1024 + n];
    chat[n] = c[n] * (1.0f + b2[2048 + n]) + b2[3072 + n];
}

// h1 = tanh(cond @ W1 + b1); fp32 h1f (B x 64) + fp8 copies into tail cols
// [1024,1088) of vbuf, hbuf, vdbuf (stride KB).
__global__ void h1_kernel(const float* __restrict__ cond, const float* __restrict__ W1,
                          const float* __restrict__ b1, float* __restrict__ h1f,
                          uint8_t* __restrict__ vbuf, uint8_t* __restrict__ hbuf,
                          uint8_t* __restrict__ vdbuf) {
    int row = blockIdx.x * 4 + (threadIdx.x >> 6);
    int j   = threadIdx.x & 63;
    const float* cr = cond + (size_t)row * C_DIM;
    float s = b1[j];
#pragma unroll 8
    for (int k = 0; k < C_DIM; ++k) s = fmaf(cr[k], W1[k * 64 + j], s);
    float t = tanhf(s);
    h1f[(size_t)row * 64 + j] = t;
    size_t o = (size_t)row * KB + 1024 + j;
    uint8_t tb = f2fp8(t);
    vbuf[o] = tb; hbuf[o] = tb; vdbuf[o] = tb;
}

// v_start ~ Bern(0.5) into vbuf cols [0,1024), 4 bytes/thread
__global__ void initv_kernel(uint8_t* __restrict__ v, uint32_t tag) {
    uint32_t g = (blockIdx.x * 256 + threadIdx.x) * 4;
    uint32_t row = g >> 10, col = g & 1023;
    uint32_t w = 0;
#pragma unroll
    for (int e = 0; e < 4; ++e)
        if (rng_u01(g + e, tag) < 0.5f) w |= (uint32_t)FP8_ONE << (8 * e);
    *(uint32_t*)(v + (size_t)row * KB + col) = w;
}

// v_data (fp32 0/1) -> vdbuf cols [0,1024), fp8 exact, 4/thread
__global__ void cast_kernel(const float* __restrict__ src, uint8_t* __restrict__ dst) {
    uint32_t g = (blockIdx.x * 256 + threadIdx.x) * 4;
    uint32_t row = g >> 10, col = g & 1023;
    f32x4 s = *(const f32x4*)(src + g);
    uint32_t w = 0;
#pragma unroll
    for (int e = 0; e < 4; ++e)
        if (s[e] >= 0.5f) w |= (uint32_t)FP8_ONE << (8 * e);
    *(uint32_t*)(dst + (size_t)row * KB + col) = w;
}

// out += scale * sum_ij (vm-vd)_ij * b_mod_ij ; b_mod[i,j] = bhat[j] + h1[i,:].Whb[:,j]
// Thread = one column j (grid B/8 x 4 col-splits); w[64] fp32 loaded once;
// h1 rows via wave-uniform addresses; fp8 state bytes (0x00/0x38) compared.
__global__ __launch_bounds__(256) void bdot_kernel(
    const uint8_t* __restrict__ vm, const uint8_t* __restrict__ vd,
    const float* __restrict__ Whbf, const float* __restrict__ bhat,
    const float* __restrict__ h1f, float* __restrict__ out, float scale) {
    const int r0 = (blockIdx.x >> 2) * 8;
    const int j  = (blockIdx.x & 3) * 256 + threadIdx.x;

    float w[64];
    const f32x4* wp = (const f32x4*)(Whbf + (size_t)j * 64);
#pragma unroll
    for (int q = 0; q < 16; ++q) {
        f32x4 v4 = wp[q];
#pragma unroll
        for (int e = 0; e < 4; ++e) w[q * 4 + e] = v4[e];
    }
    const float bj = bhat[j];

    float local = 0.0f;
#pragma unroll 2
    for (int r = 0; r < 8; ++r) {
        const float* h1r = h1f + (size_t)(r0 + r) * 64;  // uniform address
        float bm = bj;
#pragma unroll
        for (int k = 0; k < 64; ++k) bm = fmaf(h1r[k], w[k], bm);
        float d = (float)(int)(vm[(size_t)(r0 + r) * KB + j] != 0)
                - (float)(int)(vd[(size_t)(r0 + r) * KB + j] != 0);
        local = fmaf(d, bm, local);
    }
    local *= scale;
    for (int off = 32; off > 0; off >>= 1)
        local += __shfl_down(local, off, 64);
    __shared__ float wsum[4];
    int lane = threadIdx.x & 63, wave = threadIdx.x >> 6;
    if (lane == 0) wsum[wave] = local;
    __syncthreads();
    if (threadIdx.x == 0)
        atomicAdd(out, wsum[0] + wsum[1] + wsum[2] + wsum[3]);
}

// ---------------------------------------------------------------------------
extern "C" void kernel_launch(void* const* d_in, const int* in_sizes, int n_in,
                              void* d_out, int out_size, void* d_ws, size_t ws_size,
                              hipStream_t stream) {
    (void)in_sizes; (void)n_in; (void)out_size; (void)ws_size;
    const float* v_data = (const float*)d_in[0];
    const float* cond   = (const float*)d_in[1];
    const float* W      = (const float*)d_in[2];
    const float* b      = (const float*)d_in[3];
    const float* c      = (const float*)d_in[4];
    const float* W1     = (const float*)d_in[5];
    const float* b1     = (const float*)d_in[6];
    const float* W2     = (const float*)d_in[7];
    const float* b2     = (const float*)d_in[8];
    float* out = (float*)d_out;
    char*  ws  = (char*)d_ws;

    const size_t MB = 1024 * 1024;
    uint8_t* Btv  = (uint8_t*)(ws + 0 * MB);    // 1024 x 1152 fp8 (~1.2 MB)
    uint8_t* Bth  = (uint8_t*)(ws + 2 * MB);    // 1024 x 1152 fp8
    float*   Whbf = (float*)  (ws + 4 * MB);    // 1024 x 64 fp32 (256 KB)
    float*   h1f  = (float*)  (ws + 5 * MB);    // B x 64 fp32 (4 MB)
    float*   bhat = (float*)  (ws + 9 * MB);    // 4 KB
    float*   chat = (float*)  (ws + 10 * MB);   // 4 KB
    uint8_t* vbuf = (uint8_t*)(ws + 11 * MB);   // B x 1152 fp8 (18 MB)
    uint8_t* hbuf = (uint8_t*)(ws + 30 * MB);   // B x 1152 fp8
    uint8_t* vdbuf= (uint8_t*)(ws + 49 * MB);   // B x 1152 fp8
    // total ~68 MB

    hipMemsetAsync(d_out, 0, sizeof(float), stream);

    h1_kernel<<<B_ROWS / 4, 256, 0, stream>>>(cond, W1, b1, h1f, vbuf, hbuf, vdbuf);
    wpack_kernel<<<dim3(32, 32), 256, 0, stream>>>(W, Btv, Bth);
    wtail_kernel<<<(1024 * 128) / 256, 256, 0, stream>>>(W2, b, c, Btv, Bth, Whbf);
    hatvec_kernel<<<4, 256, 0, stream>>>(b, c, b2, bhat, chat);
    initv_kernel<<<(B_ROWS * 1024) / 1024, 256, 0, stream>>>(vbuf, 7u);
    cast_kernel<<<(B_ROWS * 1024) / 1024, 256, 0, stream>>>(v_data, vdbuf);

    dim3 ggrid(1024 / 128, B_ROWS / 128);  // 8 x 128 = 1024 blocks
    const float invB = 1.0f / (float)B_ROWS;

    for (int k = 0; k < K_STEPS; ++k) {
        // h ~ Bern(sigmoid(v@W + c_mod)) : A=[v|h1|0], Bt=[W^T|Whc^T|0], +chat
        gemm_ep<0><<<ggrid, 256, 0, stream>>>(vbuf, Bth, chat, hbuf, nullptr,
                                              B_ROWS, H_DIM, KB,
                                              100u + 2u * (uint32_t)k, 0.0f);
        // v ~ Bern(sigmoid(h@W + b_mod)) : A=[h|h1|0], Bt=[W|Whb^T|0], +bhat
        gemm_ep<0><<<ggrid, 256, 0, stream>>>(hbuf, Btv, bhat, vbuf, nullptr,
                                              B_ROWS, V_DIM, KB,
                                              101u + 2u * (uint32_t)k, 0.0f);
    }

    // loss*B = sum softplus(v_model@W + c_mod) - sum softplus(v_data@W + c_mod)
    //          + sum (v_model - v_data)*b_mod
    gemm_ep<1><<<ggrid, 256, 0, stream>>>(vbuf, Bth, chat, nullptr, out,
                                          B_ROWS, H_DIM, KB, 0u, invB);
    gemm_ep<1><<<ggrid, 256, 0, stream>>>(vdbuf, Bth, chat, nullptr, out,
                                          B_ROWS, H_DIM, KB, 1u, -invB);
    bdot_kernel<<<(B_ROWS / 8) * 4, 256, 0, stream>>>(vbuf, vdbuf, Whbf, bhat, h1f, out, invB);
}

// Round 6
// 1975.004 us; speedup vs baseline: 3.9172x; 1.1445x over previous
//
#include <hip/hip_runtime.h>
#include <stdint.h>

// Problem constants (match reference)
#define B_ROWS 16384
#define V_DIM  1024
#define H_DIM  1024
#define KB     1152   // padded K: 1024 state + 64 h1-tail + 64 ZERO pad (mult of 128)
#define C_DIM  64
#define P_COLS 4096   // 2*(V+H)
#define K_STEPS 25

#define FP8_ONE 0x38  // e4m3fn 1.0
#define FP8_NEG1 0xB8 // e4m3fn -1.0

typedef float f32x4 __attribute__((ext_vector_type(4)));
typedef int   v8i   __attribute__((ext_vector_type(8)));

// ---------------------------------------------------------------------------
// Counter-based RNG (lowbias32). One 32-bit hash -> two 16-bit uniforms.
// Mean-over-16384-chains loss is RNG-implementation-invariant (R1-R5).
// ---------------------------------------------------------------------------
__device__ __forceinline__ uint32_t hash32(uint32_t idx, uint32_t tagmix) {
    uint32_t x = idx * 0x9E3779B9u ^ tagmix;
    x ^= x >> 16; x *= 0x7FEB352Du;
    x ^= x >> 15; x *= 0x846CA68Bu;
    x ^= x >> 16;
    return x;
}

// async global->LDS, 16B per lane. LDS dst = wave-uniform base + lane*16.
__device__ __forceinline__ void load_lds16(const void* g, void* l) {
    __builtin_amdgcn_global_load_lds(
        (__attribute__((address_space(1))) void*)(uintptr_t)(g),
        (__attribute__((address_space(3))) void*)(l),
        16, 0, 0);
}

__device__ __forceinline__ float softplus_f(float x) {
    return fmaxf(x, 0.0f) + log1pf(__expf(-fabsf(x)));
}

__device__ __forceinline__ uint8_t f2fp8(float x) {
    int p = __builtin_amdgcn_cvt_pk_fp8_f32(x, 0.0f, 0, false);
    return (uint8_t)(p & 0xFF);
}

// ---------------------------------------------------------------------------
// fp8 GEMM C = A (MxK) * Bt^T (Bt NxK row-major), K = KB, via
// mfma_scale_f32_16x16x128_f8f6f4 with unit scales.
// R6: tile BM=128 x BN=64 (grid 2048 = 8 blocks/CU by grid; LDS 24 KB ->
// 6/CU; launch_bounds(256,5)) to fix the R4/R5 occupancy stall
// (MfmaUtil 3.8%, both pipes idle at 4 blocks/CU phase-locked).
// Wave-tile 64x32 (acc 4x2). 16B slots XOR-swizzled by row&7 on both the
// staging fetch and the fragment reads (bank-conflict-free).
// MODE 0: out_s = bernoulli(sigmoid(C + cvec)) fp8 {0,0x38}, row-stride KB
// MODE 1: atomicAdd(out_f, scale * sum(softplus(C + cvec)))
// MODE 2: out_f[row*N + col] = C   (raw fp32 store, no cvec)
// ---------------------------------------------------------------------------
template <int MODE>
__global__ __launch_bounds__(256, 5) void gemm_ep(
    const uint8_t* __restrict__ A, const uint8_t* __restrict__ Bt,
    const float* __restrict__ cvec, uint8_t* __restrict__ out_s,
    float* __restrict__ out_f, int M, int N, int K,
    uint32_t tag, float scale)
{
    constexpr int BM = 128, BN = 64, BK = 128;
    __shared__ __align__(16) uint8_t sA[BM * BK];   // 16 KB
    __shared__ __align__(16) uint8_t sB[BN * BK];   //  8 KB

    const int tid  = threadIdx.x;
    const int wave = tid >> 6;
    const int lane = tid & 63;
    const int m0 = blockIdx.y * BM;
    const int n0 = blockIdx.x * BN;
    const int wr = (wave >> 1) * 64;   // wave row offset (0/64)
    const int wc = (wave & 1) * 32;    // wave col offset (0/32)
    const int cl   = lane & 15;
    const int quad = lane >> 4;

    // Staging: 24 chunks of (8 rows x 128 B): A chunks 0..15, B chunks 16..23.
    // Wave w loads chunks [w*6, w*6+6). Lane covers row lane>>3, swizzled slot.
    const int lrow8 = lane >> 3;
    const int lcol  = ((lane & 7) ^ lrow8) << 4;
    const uint8_t* gp[6];
    uint8_t*       lp[6];
#pragma unroll
    for (int i = 0; i < 6; ++i) {
        int c = wave * 6 + i;
        if (c < 16) {
            gp[i] = A + (size_t)(m0 + c * 8 + lrow8) * K + lcol;
            lp[i] = sA + c * 8 * BK;
        } else {
            gp[i] = Bt + (size_t)(n0 + (c - 16) * 8 + lrow8) * K + lcol;
            lp[i] = sB + (c - 16) * 8 * BK;
        }
    }

    f32x4 acc[4][2] = {};
    union F8 { int4 h[2]; v8i v; };
    const int xr = cl & 7;
    const int p0 = ((2 * quad) ^ xr) << 4;
    const int p1 = ((2 * quad + 1) ^ xr) << 4;

    for (int kt = 0; kt < K; kt += BK) {
#pragma unroll
        for (int i = 0; i < 6; ++i) load_lds16(gp[i] + kt, lp[i]);
        __syncthreads();

        v8i af[4], bfr[2];
#pragma unroll
        for (int mi = 0; mi < 4; ++mi) {
            const uint8_t* rp = sA + (wr + mi * 16 + cl) * BK;
            F8 f; f.h[0] = *(const int4*)(rp + p0); f.h[1] = *(const int4*)(rp + p1);
            af[mi] = f.v;
        }
#pragma unroll
        for (int ni = 0; ni < 2; ++ni) {
            const uint8_t* rp = sB + (wc + ni * 16 + cl) * BK;
            F8 f; f.h[0] = *(const int4*)(rp + p0); f.h[1] = *(const int4*)(rp + p1);
            bfr[ni] = f.v;
        }
#pragma unroll
        for (int mi = 0; mi < 4; ++mi)
#pragma unroll
            for (int ni = 0; ni < 2; ++ni)
                acc[mi][ni] = __builtin_amdgcn_mfma_scale_f32_16x16x128_f8f6f4(
                    af[mi], bfr[ni], acc[mi][ni],
                    0, 0, 0, 0x7F7F7F7F, 0, 0x7F7F7F7F);
        __syncthreads();
    }

    // Epilogue. C/D layout: col = lane&15, row = quad*4 + reg (per 16x16 tile)
    const int row_base = m0 + wr + quad * 4;
    const int col_base = n0 + wc + cl;

    if (MODE == 0) {
        const uint32_t tagmix = tag * 0x85EBCA6Bu + 0xC2B2AE35u;
        float cv[2];
#pragma unroll
        for (int ni = 0; ni < 2; ++ni) cv[ni] = cvec[col_base + ni * 16];
#pragma unroll
        for (int mi = 0; mi < 4; ++mi) {
#pragma unroll
            for (int ni = 0; ni < 2; ++ni) {
                int col = col_base + ni * 16;
#pragma unroll
                for (int pr = 0; pr < 2; ++pr) {      // reg pairs (0,1),(2,3)
                    int row0 = row_base + mi * 16 + pr * 2;
                    uint32_t h = hash32((uint32_t)((row0 >> 1) * KB + col), tagmix);
                    float u0 = (float)(h & 0xFFFFu) * 1.52587890625e-5f;
                    float u1 = (float)(h >> 16)     * 1.52587890625e-5f;
#pragma unroll
                    for (int r2 = 0; r2 < 2; ++r2) {
                        float x = acc[mi][ni][pr * 2 + r2] + cv[ni];
                        float p = 1.0f / (1.0f + __expf(-x));
                        float u = r2 ? u1 : u0;
                        out_s[(size_t)(row0 + r2) * KB + col] =
                            (u < p) ? (uint8_t)FP8_ONE : (uint8_t)0;
                    }
                }
            }
        }
    } else if (MODE == 1) {
        float cv[2];
#pragma unroll
        for (int ni = 0; ni < 2; ++ni) cv[ni] = cvec[col_base + ni * 16];
        float local = 0.0f;
#pragma unroll
        for (int mi = 0; mi < 4; ++mi)
#pragma unroll
            for (int ni = 0; ni < 2; ++ni)
#pragma unroll
                for (int r = 0; r < 4; ++r)
                    local += softplus_f(acc[mi][ni][r] + cv[ni]);
        local *= scale;
        for (int off = 32; off > 0; off >>= 1)
            local += __shfl_down(local, off, 64);
        __shared__ float wsum[4];
        if (lane == 0) wsum[wave] = local;
        __syncthreads();
        if (tid == 0)
            atomicAdd(out_f, wsum[0] + wsum[1] + wsum[2] + wsum[3]);
    } else {
#pragma unroll
        for (int mi = 0; mi < 4; ++mi)
#pragma unroll
            for (int ni = 0; ni < 2; ++ni)
#pragma unroll
                for (int r = 0; r < 4; ++r) {
                    int row = row_base + mi * 16 + r;
                    int col = col_base + ni * 16;
                    out_f[(size_t)row * N + col] = acc[mi][ni][r];
                }
    }
}

// ---------------------------------------------------------------------------
// W (VxH fp32) -> fp8 B-operands (row stride KB):
//   Btv[n][k] = W[n][k]  (v-GEMM)    Bth[n][k] = W[k][n]  (h-GEMM)
// ---------------------------------------------------------------------------
__global__ void wpack_kernel(const float* __restrict__ W,
                             uint8_t* __restrict__ Btv, uint8_t* __restrict__ Bth) {
    __shared__ float tile[32][33];
    int bx = blockIdx.x * 32, by = blockIdx.y * 32;
    int tx = threadIdx.x & 31, ty = threadIdx.x >> 5;
#pragma unroll
    for (int r = ty; r < 32; r += 8) {
        float v = W[(size_t)(by + r) * H_DIM + bx + tx];
        Btv[(size_t)(by + r) * KB + bx + tx] = f2fp8(v);
        tile[r][tx] = v;
    }
    __syncthreads();
#pragma unroll
    for (int r = ty; r < 32; r += 8)
        Bth[(size_t)(bx + r) * KB + by + tx] = f2fp8(tile[tx][r]);
}

// Tail cols [1024,1152) of Btv/Bth: rank-64 modulation factors + zero pad.
// Also fills BtP (the bdot-replacement B operand, 128 rows x KB):
//   BtP[k'][j] = Whb[k'][j] (k'<64), BtP[64][j] = bhat[j], rows 65..127 = 0
// (BtP tail cols pre-zeroed by memset).
__global__ void wtail_kernel(const float* __restrict__ W2, const float* __restrict__ b,
                             const float* __restrict__ c, const float* __restrict__ b2,
                             uint8_t* __restrict__ Btv, uint8_t* __restrict__ Bth,
                             uint8_t* __restrict__ BtP) {
    int gid = blockIdx.x * 256 + threadIdx.x;   // 1024 * 128
    int n = gid >> 7, kp = gid & 127;
    if (kp < 64) {
        float wc = W2[(size_t)kp * P_COLS + 2048 + n] * c[n] + W2[(size_t)kp * P_COLS + 3072 + n];
        float wb = W2[(size_t)kp * P_COLS + n] * b[n]        + W2[(size_t)kp * P_COLS + 1024 + n];
        Bth[(size_t)n * KB + 1024 + kp] = f2fp8(wc);
        Btv[(size_t)n * KB + 1024 + kp] = f2fp8(wb);
        BtP[(size_t)kp * KB + n] = f2fp8(wb);
    } else {
        Bth[(size_t)n * KB + 1024 + kp] = 0;    // zero pad
        Btv[(size_t)n * KB + 1024 + kp] = 0;
        if (kp == 64) {
            float bh = b[n] * (1.0f + b2[n]) + b2[1024 + n];
            BtP[(size_t)64 * KB + n] = f2fp8(bh);
        } else {
            BtP[(size_t)kp * KB + n] = 0;
        }
    }
}

// Row-independent modulation constants (fp32, used as GEMM cvec):
__global__ void hatvec_kernel(const float* __restrict__ b, const float* __restrict__ c,
                              const float* __restrict__ b2,
                              float* __restrict__ bhat, float* __restrict__ chat) {
    int n = blockIdx.x * 256 + threadIdx.x;
    bhat[n] = b[n] * (1.0f + b2[n]) + b2[1024 + n];
    chat[n] = c[n] * (1.0f + b2[2048 + n]) + b2[3072 + n];
}

// h1 = tanh(cond @ W1 + b1); fp32 h1f + fp8 copies into tail cols of buffers.
__global__ void h1_kernel(const float* __restrict__ cond, const float* __restrict__ W1,
                          const float* __restrict__ b1, float* __restrict__ h1f,
                          uint8_t* __restrict__ vbuf, uint8_t* __restrict__ hbuf,
                          uint8_t* __restrict__ vdbuf) {
    int row = blockIdx.x * 4 + (threadIdx.x >> 6);
    int j   = threadIdx.x & 63;
    const float* cr = cond + (size_t)row * C_DIM;
    float s = b1[j];
#pragma unroll 8
    for (int k = 0; k < C_DIM; ++k) s = fmaf(cr[k], W1[k * 64 + j], s);
    float t = tanhf(s);
    h1f[(size_t)row * 64 + j] = t;
    size_t o = (size_t)row * KB + 1024 + j;
    uint8_t tb = f2fp8(t);
    vbuf[o] = tb; hbuf[o] = tb; vdbuf[o] = tb;
}

// v_start ~ Bern(0.5) into vbuf cols [0,1024)
__global__ void initv_kernel(uint8_t* __restrict__ v, uint32_t tag) {
    uint32_t g = (blockIdx.x * 256 + threadIdx.x) * 4;
    uint32_t row = g >> 10, col = g & 1023;
    uint32_t tagmix = tag * 0x85EBCA6Bu + 0xC2B2AE35u;
    uint32_t w = 0;
#pragma unroll
    for (int e = 0; e < 4; ++e)
        if ((hash32(g + e, tagmix) >> 8) * 5.9604644775390625e-8f < 0.5f)
            w |= (uint32_t)FP8_ONE << (8 * e);
    *(uint32_t*)(v + (size_t)row * KB + col) = w;
}

// v_data (fp32 0/1) -> vdbuf cols [0,1024), fp8 exact
__global__ void cast_kernel(const float* __restrict__ src, uint8_t* __restrict__ dst) {
    uint32_t g = (blockIdx.x * 256 + threadIdx.x) * 4;
    uint32_t row = g >> 10, col = g & 1023;
    f32x4 s = *(const f32x4*)(src + g);
    uint32_t w = 0;
#pragma unroll
    for (int e = 0; e < 4; ++e)
        if (s[e] >= 0.5f) w |= (uint32_t)FP8_ONE << (8 * e);
    *(uint32_t*)(dst + (size_t)row * KB + col) = w;
}

// T = vm - vd in fp8, written IN-PLACE over vd (tails cancel to exact 0).
// Per byte: equal -> 0; else vm==0x38 -> +1 (0x38), vm==0 -> -1 (0xB8).
__global__ void tdiff_kernel(uint8_t* __restrict__ vd, const uint8_t* __restrict__ vm) {
    size_t g = ((size_t)blockIdx.x * 256 + threadIdx.x) * 4;
    uint32_t a = *(const uint32_t*)(vm + g);
    uint32_t d = *(const uint32_t*)(vd + g);
    uint32_t t = 0;
#pragma unroll
    for (int e = 0; e < 4; ++e) {
        uint32_t vb = (a >> (8 * e)) & 0xFF, db = (d >> (8 * e)) & 0xFF;
        if (vb != db) t |= (vb ? (uint32_t)FP8_ONE : (uint32_t)FP8_NEG1) << (8 * e);
    }
    *(uint32_t*)(vd + g) = t;
}

// out += scale * sum_i [ P[i][64] + sum_k h1f[i][k] * P[i][k] ]
__global__ __launch_bounds__(256) void preduce_kernel(
    const float* __restrict__ P, const float* __restrict__ h1f,
    float* __restrict__ out, float scale) {
    int row = blockIdx.x * 256 + threadIdx.x;
    const f32x4* pr = (const f32x4*)(P + (size_t)row * 128);
    const f32x4* hr = (const f32x4*)(h1f + (size_t)row * 64);
    float local = P[(size_t)row * 128 + 64];
#pragma unroll
    for (int q = 0; q < 16; ++q) {
        f32x4 pv = pr[q], hv = hr[q];
#pragma unroll
        for (int e = 0; e < 4; ++e) local = fmaf(hv[e], pv[e], local);
    }
    local *= scale;
    for (int off = 32; off > 0; off >>= 1)
        local += __shfl_down(local, off, 64);
    __shared__ float wsum[4];
    int lane = threadIdx.x & 63, wave = threadIdx.x >> 6;
    if (lane == 0) wsum[wave] = local;
    __syncthreads();
    if (threadIdx.x == 0)
        atomicAdd(out, wsum[0] + wsum[1] + wsum[2] + wsum[3]);
}

// ---------------------------------------------------------------------------
extern "C" void kernel_launch(void* const* d_in, const int* in_sizes, int n_in,
                              void* d_out, int out_size, void* d_ws, size_t ws_size,
                              hipStream_t stream) {
    (void)in_sizes; (void)n_in; (void)out_size; (void)ws_size;
    const float* v_data = (const float*)d_in[0];
    const float* cond   = (const float*)d_in[1];
    const float* W      = (const float*)d_in[2];
    const float* b      = (const float*)d_in[3];
    const float* c      = (const float*)d_in[4];
    const float* W1     = (const float*)d_in[5];
    const float* b1     = (const float*)d_in[6];
    const float* W2     = (const float*)d_in[7];
    const float* b2     = (const float*)d_in[8];
    float* out = (float*)d_out;
    char*  ws  = (char*)d_ws;

    const size_t MB = 1024 * 1024;
    uint8_t* Btv  = (uint8_t*)(ws + 0 * MB);    // 1024 x KB fp8
    uint8_t* Bth  = (uint8_t*)(ws + 2 * MB);    // 1024 x KB fp8
    uint8_t* BtP  = (uint8_t*)(ws + 4 * MB);    // 128 x KB fp8 (144 KB)
    float*   h1f  = (float*)  (ws + 5 * MB);    // B x 64 fp32 (4 MB)
    float*   bhat = (float*)  (ws + 9 * MB);
    float*   chat = (float*)  (ws + 10 * MB);
    float*   Pbuf = (float*)  (ws + 11 * MB);   // B x 128 fp32 (8 MB)
    uint8_t* vbuf = (uint8_t*)(ws + 20 * MB);   // B x KB fp8 (18.9 MB)
    uint8_t* hbuf = (uint8_t*)(ws + 40 * MB);
    uint8_t* vdbuf= (uint8_t*)(ws + 60 * MB);
    // total ~79 MB

    hipMemsetAsync(d_out, 0, sizeof(float), stream);
    hipMemsetAsync(BtP, 0, (size_t)128 * KB, stream);  // tail cols + zero rows

    h1_kernel<<<B_ROWS / 4, 256, 0, stream>>>(cond, W1, b1, h1f, vbuf, hbuf, vdbuf);
    wpack_kernel<<<dim3(32, 32), 256, 0, stream>>>(W, Btv, Bth);
    wtail_kernel<<<(1024 * 128) / 256, 256, 0, stream>>>(W2, b, c, b2, Btv, Bth, BtP);
    hatvec_kernel<<<4, 256, 0, stream>>>(b, c, b2, bhat, chat);
    initv_kernel<<<(B_ROWS * 1024) / 1024, 256, 0, stream>>>(vbuf, 7u);
    cast_kernel<<<(B_ROWS * 1024) / 1024, 256, 0, stream>>>(v_data, vdbuf);

    dim3 ggrid(1024 / 64, B_ROWS / 128);  // 16 x 128 = 2048 blocks (8/CU)
    const float invB = 1.0f / (float)B_ROWS;

    for (int k = 0; k < K_STEPS; ++k) {
        gemm_ep<0><<<ggrid, 256, 0, stream>>>(vbuf, Bth, chat, hbuf, nullptr,
                                              B_ROWS, H_DIM, KB,
                                              100u + 2u * (uint32_t)k, 0.0f);
        gemm_ep<0><<<ggrid, 256, 0, stream>>>(hbuf, Btv, bhat, vbuf, nullptr,
                                              B_ROWS, V_DIM, KB,
                                              101u + 2u * (uint32_t)k, 0.0f);
    }

    // loss*B = sum softplus(vm@W + c_mod) - sum softplus(vd@W + c_mod)
    //          + sum (vm - vd)*b_mod      (rank-64 factored, GEMM-shaped)
    gemm_ep<1><<<ggrid, 256, 0, stream>>>(vbuf, Bth, chat, nullptr, out,
                                          B_ROWS, H_DIM, KB, 0u, invB);
    gemm_ep<1><<<ggrid, 256, 0, stream>>>(vdbuf, Bth, chat, nullptr, out,
                                          B_ROWS, H_DIM, KB, 1u, -invB);
    tdiff_kernel<<<(B_ROWS * KB) / 1024, 256, 0, stream>>>(vdbuf, vbuf);
    gemm_ep<2><<<dim3(2, B_ROWS / 128), 256, 0, stream>>>(vdbuf, BtP, nullptr,
                                                          nullptr, Pbuf,
                                                          B_ROWS, 128, KB, 0u, 0.0f);
    preduce_kernel<<<B_ROWS / 256, 256, 0, stream>>>(Pbuf, h1f, out, invB);
}